// Round 6
// baseline (1007.358 us; speedup 1.0000x reference)
//
#include <hip/hip_runtime.h>

typedef __bf16 bf16_t;
typedef __bf16 bf16x8 __attribute__((ext_vector_type(8)));
typedef float f32x4 __attribute__((ext_vector_type(4)));
typedef unsigned u32x4 __attribute__((ext_vector_type(4)));
typedef unsigned long long u64;

static constexpr int BB = 32, SS = 128, WW = 16, EE = 256, CDm = 64, HH = 512, PP = 256;
static constexpr int EC = 320;    // E + CD
static constexpr int H2 = 1024;   // 2H
static constexpr int G6 = 3072;   // 6H
static constexpr int NKT = 28;    // 16 h-ktiles + 12 x-ktiles (x padded 320->384)
static constexpr int NKTX = 12;

__device__ __forceinline__ float sigm(float x){ return 1.f/(1.f + expf(-x)); }

#define ALOAD(p)    __hip_atomic_load((p),  __ATOMIC_RELAXED, __HIP_MEMORY_SCOPE_AGENT)
#define ASTORE(p,v) __hip_atomic_store((p),(v),__ATOMIC_RELAXED, __HIP_MEMORY_SCOPE_AGENT)

// ---- coherent (LLC) memory helpers ------------------------------------------------------
__device__ __forceinline__ unsigned ld_flag(const unsigned* p){
  unsigned r;
  asm volatile("global_load_dword %0, %1, off sc0 sc1\n\ts_waitcnt vmcnt(0)"
               : "=&v"(r) : "v"(p) : "memory");
  return r;
}
__device__ __forceinline__ void ld16(u32x4& d, const void* p){
  asm volatile("global_load_dwordx4 %0, %1, off sc0 sc1" : "=&v"(d) : "v"(p) : "memory");
}
__device__ __forceinline__ void st16(void* p, u32x4 v){
  asm volatile("global_store_dwordx4 %0, %1, off sc0 sc1" :: "v"(p), "v"(v) : "memory");
}
__device__ __forceinline__ void st32c(unsigned* p, unsigned v){
  asm volatile("global_store_dword %0, %1, off sc0 sc1" :: "v"(p), "v"(v) : "memory");
}
__device__ __forceinline__ void vm_drain(){
  asm volatile("s_waitcnt vmcnt(0)" ::: "memory");
  __builtin_amdgcn_sched_barrier(0);
}

// ---------------- embedding ---------------------------------------------------------------
__global__ void k_embed(const int* __restrict__ seq, const float* __restrict__ embed_w,
                        float* __restrict__ x, float* __restrict__ mask){
  int bs = blockIdx.x; int c = threadIdx.x;
  int wid = seq[bs];
  x[(size_t)bs*EC + c] = tanhf(embed_w[(size_t)wid*EE + c]);
  if (c == 0) mask[bs] = (wid > 0) ? 1.f : 0.f;
}

// ---------------- char means --------------------------------------------------------------
__global__ void k_cbar(const int* __restrict__ seq_char, const float* __restrict__ cemb,
                       float* __restrict__ cbar){
  int bs = blockIdx.x; int c = threadIdx.x;  // 64 threads
  float ce[WW];
  #pragma unroll
  for (int p = 0; p < WW; ++p){
    int id = seq_char[bs*WW + p];
    ce[p] = cemb[(size_t)id*CDm + c];
  }
  #pragma unroll
  for (int k = 0; k < 8; ++k){
    float s = 0.f;
    #pragma unroll
    for (int p = 0; p < 9; ++p) s += ce[k+p];
    cbar[(size_t)bs*512 + c*8 + k] = s * (1.f/9.f);
  }
}

// ---------------- x sliding means ---------------------------------------------------------
__global__ __launch_bounds__(64) void k_xbar(const float* __restrict__ x, float* __restrict__ xbar){
  __shared__ float xl[64][129];
  int gid = blockIdx.x*64 + threadIdx.x;  // 0..10239
  int b = gid / EC, c = gid % EC;
  int tl = threadIdx.x;
  for (int t = 0; t < SS; ++t) xl[tl][t] = x[((size_t)b*SS + t)*EC + c];
  float s = 0.f;
  for (int t = 0; t < 65; ++t) s += xl[tl][t];
  const float inv = 1.f/65.f;
  float* o = &xbar[(size_t)(b*EC + c)*64];
  o[0] = s*inv;
  for (int k = 1; k < 64; ++k){ s += xl[tl][k+64] - xl[tl][k-1]; o[k] = s*inv; }
}

// ---------------- generic fp32 tiled GEMM -------------------------------------------------
template<int BM,int BN,int TM,int TN>
__global__ __launch_bounds__(256) void k_gemm(const float* __restrict__ A,
    const float* __restrict__ Wm, float* __restrict__ part,
    int M, int N, int K, int kslice){
  __shared__ float As[32][BM+4];
  __shared__ float Ws[32][BN+4];
  const int tid = threadIdx.x;
  const int tx = tid & 15, ty = tid >> 4;
  const int m0 = blockIdx.x*BM, n0 = blockIdx.y*BN, ks = blockIdx.z;
  const int kb = ks*kslice;
  float acc[TM][TN];
  #pragma unroll
  for (int i = 0; i < TM; ++i)
    #pragma unroll
    for (int j = 0; j < TN; ++j) acc[i][j] = 0.f;
  for (int kt = 0; kt < kslice; kt += 32){
    constexpr int AIT = (BM*8)/256;
    #pragma unroll
    for (int it = 0; it < AIT; ++it){
      int ch = tid + it*256;
      int r = ch >> 3, kc = (ch & 7)*4;
      float4 v = *(const float4*)(A + (size_t)(m0+r)*K + kb + kt + kc);
      As[kc+0][r]=v.x; As[kc+1][r]=v.y; As[kc+2][r]=v.z; As[kc+3][r]=v.w;
    }
    constexpr int WIT = (BN*8)/256;
    #pragma unroll
    for (int it = 0; it < WIT; ++it){
      int ch = tid + it*256;
      int r = ch >> 3, kc = (ch & 7)*4;
      float4 v = *(const float4*)(Wm + (size_t)(n0+r)*K + kb + kt + kc);
      Ws[kc+0][r]=v.x; Ws[kc+1][r]=v.y; Ws[kc+2][r]=v.z; Ws[kc+3][r]=v.w;
    }
    __syncthreads();
    #pragma unroll
    for (int kk = 0; kk < 32; ++kk){
      float a[TM], wv[TN];
      #pragma unroll
      for (int i = 0; i < TM; ++i) a[i] = As[kk][ty*TM+i];
      #pragma unroll
      for (int j = 0; j < TN; ++j) wv[j] = Ws[kk][tx*TN+j];
      #pragma unroll
      for (int i = 0; i < TM; ++i)
        #pragma unroll
        for (int j = 0; j < TN; ++j) acc[i][j] = fmaf(a[i], wv[j], acc[i][j]);
    }
    __syncthreads();
  }
  #pragma unroll
  for (int i = 0; i < TM; ++i){
    int row = m0 + ty*TM + i;
    #pragma unroll
    for (int j = 0; j < TN; ++j){
      int col = n0 + tx*TN + j;
      part[((size_t)ks*M + row)*N + col] = acc[i][j];
    }
  }
}

// ---------------- finalize partials -------------------------------------------------------
__global__ __launch_bounds__(64) void k_fin(const float* __restrict__ part,
    const float* __restrict__ bias, float* __restrict__ out,
    int M, int N, int KS, int ldc, int act){
  int col = blockIdx.x*64 + threadIdx.x;
  int row = blockIdx.y;
  float v = bias ? bias[col] : 0.f;
  for (int ks = 0; ks < KS; ++ks) v += part[((size_t)ks*M + row)*N + col];
  if (act) v = tanhf(v);
  out[(size_t)row*ldc + col] = v;
}

// ---------------- pack LSTM weights: interleaved-col B-frags ------------------------------
// Wp2[dir(2)][ub(64)][kt(28)][nt(2)][lane(64)][8]
// col c_local = lane&15 -> u_local=c>>2, gate=c&3; orig row = gate*512 + ub*8 + nt*4 + u_local
__global__ __launch_bounds__(64) void k_packw2(const float* __restrict__ fWih, const float* __restrict__ fWhh,
    const float* __restrict__ bWih, const float* __restrict__ bWhh, bf16_t* __restrict__ Wp2){
  int id = blockIdx.x;               // 2*64*28
  int kt = id % NKT; id /= NKT;
  int ub = id % 64; int dir = id / 64;
  int l = threadIdx.x;
  const float* Whh = dir ? bWhh : fWhh;
  const float* Wih = dir ? bWih : fWih;
  int cl = l & 15, ul = cl >> 2, g = cl & 3;
  int krow = (l >> 4)*8;
  for (int nt = 0; nt < 2; ++nt){
    int row = g*512 + ub*8 + nt*4 + ul;
    bf16_t* dst = &Wp2[((((size_t)(dir*64+ub)*NKT + kt)*2 + nt)*64 + l)*8];
    if (kt < 16){
      const float* src = &Whh[(size_t)row*512 + kt*32 + krow];
      #pragma unroll
      for (int r = 0; r < 8; ++r) dst[r] = (bf16_t)src[r];
    } else {
      int kx = (kt-16)*32 + krow;
      if (kx + 8 <= 320){
        const float* src = &Wih[(size_t)row*320 + kx];
        #pragma unroll
        for (int r = 0; r < 8; ++r) dst[r] = (bf16_t)src[r];
      } else {
        #pragma unroll
        for (int r = 0; r < 8; ++r) dst[r] = (bf16_t)0.f;
      }
    }
  }
}

// ---------------- pack decoder Whh: Whp[wg(64)][nt(3)][kt(32)][lane][8] -------------------
__global__ __launch_bounds__(64) void k_packdw(const float* __restrict__ W, bf16_t* __restrict__ Wo){
  int id = blockIdx.x;               // 64*3*32
  int kt = id % 32; id /= 32;
  int nt = id % 3;  int wg = id / 3;
  int l = threadIdx.x;
  int col = nt*1024 + wg*16 + (l & 15);
  int k0 = kt*32 + (l >> 4)*8;
  bf16_t* dst = Wo + (((size_t)(wg*3 + nt)*32 + kt)*64 + l)*8;
  const float* src = W + (size_t)col*1024 + k0;
  #pragma unroll
  for (int r = 0; r < 8; ++r) dst[r] = (bf16_t)src[r];
}

// ---------------- pack proj_w: Ppw[wg(16)][kt(32)][lane][8] -------------------------------
__global__ __launch_bounds__(64) void k_packpw(const float* __restrict__ W, bf16_t* __restrict__ Wo){
  int id = blockIdx.x;               // 16*32
  int kt = id & 31, wg = id >> 5;
  int l = threadIdx.x;
  int col = wg*16 + (l & 15);
  int k0 = kt*32 + (l >> 4)*8;
  bf16_t* dst = Wo + (((size_t)wg*32 + kt)*64 + l)*8;
  const float* src = W + (size_t)col*1024 + k0;
  #pragma unroll
  for (int r = 0; r < 8; ++r) dst[r] = (bf16_t)src[r];
}

// ---------------- pack x into A-fragment order --------------------------------------------
__global__ __launch_bounds__(64) void k_packx(const float* __restrict__ x, bf16_t* __restrict__ xp){
  int id = blockIdx.x;
  int ktx = id % NKTX; id /= NKTX;
  int mt = id & 1; int t = id >> 1;        // 0..127
  int l = threadIdx.x;
  int b = (l & 15) + 16*mt;
  int c = ktx*32 + (l >> 4)*8;
  bf16_t* dst = &xp[(((size_t)t*2 + mt)*NKTX + ktx)*64*8 + (size_t)l*8];
  if (c + 8 <= EC){
    const float* src = &x[((size_t)b*SS + t)*EC + c];
    #pragma unroll
    for (int r = 0; r < 8; ++r) dst[r] = (bf16_t)src[r];
  } else {
    #pragma unroll
    for (int r = 0; r < 8; ++r) dst[r] = (bf16_t)0.f;
  }
}

// ---------------- zero control region through the coherence point -------------------------
__global__ __launch_bounds__(256) void k_zero(unsigned int* __restrict__ base, int n){
  int i = blockIdx.x*256 + threadIdx.x;
  if (i < n) ASTORE(base + i, 0u);
}

// ---------------- pack decoder h0 ---------------------------------------------------------
__global__ __launch_bounds__(64) void k_hprep(const float* __restrict__ seq_repr,
                                              bf16_t* __restrict__ hdp){
  int mt = blockIdx.x >> 5, kt = blockIdx.x & 31, l = threadIdx.x;
  int b = mt*16 + (l & 15);
  int jb = kt*32 + (l >> 4)*8;
  const float* src = &seq_repr[((size_t)b*SS + 127)*H2 + jb];
  unsigned* dst = (unsigned*)(hdp + (((size_t)mt*32 + kt)*64 + l)*8);
  #pragma unroll
  for (int p = 0; p < 4; ++p){
    unsigned pk = (unsigned)__builtin_bit_cast(unsigned short, (bf16_t)src[2*p])
                | ((unsigned)__builtin_bit_cast(unsigned short, (bf16_t)src[2*p+1]) << 16);
    ASTORE(dst + p, pk);
  }
}

// ---------------- persistent BiLSTM: 128 x 1-wave WGs, full-K per wave, no barriers -------
// wave = (dir, ub): 8 hidden units x 4 gates = 32 cols (2 n-tiles), K = 896 (28 ktiles).
// h exchange: hp[ph][dir][m][kt(16)][lane][8] bf16, coherent 16B ops; 1 flag per wave;
// every wave polls ALL 64 peer flags of its dir (producer set == consumer set -> race-free).
__global__ __launch_bounds__(64, 1) void k_lstm(const bf16_t* __restrict__ Wp2,
    const bf16_t* __restrict__ xp, bf16_t* __restrict__ hp,
    const float* __restrict__ fb, const float* __restrict__ bb,
    float* __restrict__ seq_repr, unsigned* __restrict__ lf){
  const int wg = blockIdx.x;
  const int dir = wg >> 6, ub = wg & 63;
  const int lane = threadIdx.x;
  __shared__ __align__(16) bf16_t Wl[NKT*2*64*8];   // 57344 B
  __shared__ float red[32*33 + 1];                  // 4228 B
  __shared__ __align__(16) bf16_t tr[32*8];         // 512 B

  // weights -> LDS (one-time)
  {
    const uint4* src = (const uint4*)(Wp2 + ((size_t)(dir*64 + ub))*NKT*2*64*8);
    uint4* dst = (uint4*)Wl;
    #pragma unroll
    for (int i = 0; i < 56; ++i) dst[lane + i*64] = src[lane + i*64];
  }
  // per-lane gate/bias mapping
  const int gb = lane & 31;          // batch for gates phase
  const int up = lane >> 5;          // unit parity: uu = up + 2k
  float bias[16];
  {
    const float* bv = dir ? bb : fb;
    #pragma unroll
    for (int g = 0; g < 4; ++g)
      #pragma unroll
      for (int k = 0; k < 4; ++k)
        bias[g*4 + k] = bv[g*512 + ub*8 + up + 2*k];
  }
  float cst[4] = {0.f, 0.f, 0.f, 0.f};
  const int wri = (lane & 3)*8 + ((lane >> 2) & 3);   // partial red row: g*8 + u_local (nt adds 4)
  const int wboff = (lane >> 4)*4;                     // write b-offset base (m adds 16)
  __syncthreads();

  for (int t = 0; t < SS; ++t){
    const int ph = t & 1;
    const int s = dir ? ((SS - t) & 127) : t;
    f32x4 acc[2][2];
    {
      f32x4 z = {0.f,0.f,0.f,0.f};
      acc[0][0]=z; acc[0][1]=z; acc[1][0]=z; acc[1][1]=z;
    }
    // ---- x part: loads + MFMAs (pre-poll, overlaps peers' publish) ---------------------
    const bf16_t* xb = xp + (size_t)s*2*NKTX*64*8;
    #pragma unroll
    for (int i = 0; i < NKTX; ++i){
      bf16x8 a0 = *reinterpret_cast<const bf16x8*>(xb + (((size_t)0*NKTX + i)*64 + lane)*8);
      bf16x8 a1 = *reinterpret_cast<const bf16x8*>(xb + (((size_t)1*NKTX + i)*64 + lane)*8);
      #pragma unroll
      for (int nt = 0; nt < 2; ++nt){
        bf16x8 Bf = *reinterpret_cast<const bf16x8*>(&Wl[((((size_t)(16+i))*2 + nt)*64 + lane)*8]);
        acc[0][nt] = __builtin_amdgcn_mfma_f32_16x16x32_bf16(a0, Bf, acc[0][nt], 0, 0, 0);
        acc[1][nt] = __builtin_amdgcn_mfma_f32_16x16x32_bf16(a1, Bf, acc[1][nt], 0, 0, 0);
      }
    }
    // ---- poll ALL 64 peer flags of this dir (1 per lane) -------------------------------
    if (t > 0){
      const unsigned* fp = lf + ((size_t)(dir*64 + lane))*16;
      unsigned tgt = (unsigned)t;
      for(;;){
        unsigned v = ld_flag(fp);
        if (__ballot(v < tgt) == 0ull) break;
        __builtin_amdgcn_s_sleep(1);
      }
    }
    // ---- h loads (coherent) + MFMAs ----------------------------------------------------
    const bf16_t* hb = hp + ((size_t)(ph*2 + dir))*2*16*64*8;
    u32x4 hr[16][2];
    #pragma unroll
    for (int i = 0; i < 16; ++i){
      ld16(hr[i][0], hb + (((size_t)0*16 + i)*64 + lane)*8);
      ld16(hr[i][1], hb + (((size_t)1*16 + i)*64 + lane)*8);
    }
    vm_drain();
    #pragma unroll
    for (int i = 0; i < 16; ++i){
      bf16x8 a0 = __builtin_bit_cast(bf16x8, hr[i][0]);
      bf16x8 a1 = __builtin_bit_cast(bf16x8, hr[i][1]);
      #pragma unroll
      for (int nt = 0; nt < 2; ++nt){
        bf16x8 Bf = *reinterpret_cast<const bf16x8*>(&Wl[(((size_t)i*2 + nt)*64 + lane)*8]);
        acc[0][nt] = __builtin_amdgcn_mfma_f32_16x16x32_bf16(a0, Bf, acc[0][nt], 0, 0, 0);
        acc[1][nt] = __builtin_amdgcn_mfma_f32_16x16x32_bf16(a1, Bf, acc[1][nt], 0, 0, 0);
      }
    }
    // ---- wave-local transpose: acc -> red[g*8+uu][b] (stride 33, conflict-light) -------
    #pragma unroll
    for (int m = 0; m < 2; ++m)
      #pragma unroll
      for (int nt = 0; nt < 2; ++nt)
        *(f32x4*)&red[(wri + nt*4)*33 + wboff + 16*m] = acc[m][nt];
    // (same-wave ds ordering; compiler inserts lgkmcnt before dependent reads)
    // ---- gates: lane = (b, up); units uu = up+2k ---------------------------------------
    float hv[4];
    #pragma unroll
    for (int k = 0; k < 4; ++k){
      int uu = up + 2*k;
      float gi_ = red[(0*8 + uu)*33 + gb] + bias[0*4 + k];
      float gf_ = red[(1*8 + uu)*33 + gb] + bias[1*4 + k];
      float gg_ = red[(2*8 + uu)*33 + gb] + bias[2*4 + k];
      float go_ = red[(3*8 + uu)*33 + gb] + bias[3*4 + k];
      float ii = sigm(gi_), ff = sigm(gf_), g2 = tanhf(gg_), oo = sigm(go_);
      float c = ff*cst[k] + ii*g2;
      cst[k] = c;
      hv[k] = oo*tanhf(c);
      tr[gb*8 + uu] = (bf16_t)hv[k];
    }
    // ---- publish h: consumer-frag layout, 16B coalesced stores -------------------------
    if (lane < 32){
      int m = lane >> 4, bg = lane & 15;
      u32x4 v = *(const u32x4*)&tr[(bg + 16*m)*8];
      bf16_t* dsth = hp + ((((size_t)((ph^1)*2 + dir)*2 + m)*16 + (ub >> 2))*64
                     + (bg + 16*(ub & 3)))*8;
      st16(dsth, v);
    }
    vm_drain();                       // only the hp stores (seq_repr from prev step done)
    if (lane == 0)
      st32c(lf + ((size_t)(dir*64 + ub))*16, (unsigned)(t+1));
    // ---- seq_repr stores (after flag; drained by next step's vm_drain) -----------------
    {
      int s_out = dir ? (127 - t) : t;
      float* so = &seq_repr[((size_t)gb*SS + s_out)*H2 + dir*HH + ub*8 + up];
      #pragma unroll
      for (int k = 0; k < 4; ++k) so[2*k] = hv[k];
    }
  }
}

// ---------------- attention ---------------------------------------------------------------
__global__ __launch_bounds__(256) void k_ta(const int* __restrict__ classes,
    const float* __restrict__ cls_emb, const float* __restrict__ attend, float* __restrict__ ta){
  int c = blockIdx.x;
  __shared__ float t2[EE];
  int tid = threadIdx.x;
  int ci = classes[c];
  t2[tid] = tanhf(tanhf(cls_emb[(size_t)ci*EE + tid]));
  __syncthreads();
  for (int r = 0; r < 4; ++r){
    int h = r*256 + tid;
    float acc = 0.f;
    for (int e = 0; e < EE; ++e) acc = fmaf(t2[e], attend[(size_t)e*H2 + h], acc);
    ta[c*H2 + h] = tanhf(acc);
  }
}

__global__ __launch_bounds__(256) void k_ctx(const float* __restrict__ ta,
    const float* __restrict__ seq_repr, const float* __restrict__ mask, float* __restrict__ ctx){
  int c = blockIdx.x, b = blockIdx.y;
  __shared__ float ta_l[H2];
  __shared__ float ps[128][2];
  __shared__ float sc[128];
  int tid = threadIdx.x;
  for (int i = tid; i < H2; i += 256) ta_l[i] = ta[c*H2 + i];
  __syncthreads();
  {
    int tt = tid >> 1, half = tid & 1;
    const float* row = &seq_repr[((size_t)b*SS + tt)*H2 + half*512];
    const float* tl = &ta_l[half*512];
    float p = 0.f;
    for (int i = 0; i < 512; i += 4){
      float4 v = *(const float4*)&row[i];
      p = fmaf(tl[i], v.x, p);   p = fmaf(tl[i+1], v.y, p);
      p = fmaf(tl[i+2], v.z, p); p = fmaf(tl[i+3], v.w, p);
    }
    ps[tt][half] = p;
  }
  __syncthreads();
  if (tid < 128){
    float s = (ps[tid][0] + ps[tid][1]) * 128.f * mask[b*SS + tid];
    sc[tid] = tanhf(s);
  }
  __syncthreads();
  {
    int h = tid*4;
    float4 a = {0.f,0.f,0.f,0.f};
    for (int t = 0; t < SS; ++t){
      float s = sc[t];
      float4 v = *(const float4*)&seq_repr[((size_t)b*SS + t)*H2 + h];
      a.x = fmaf(s, v.x, a.x); a.y = fmaf(s, v.y, a.y);
      a.z = fmaf(s, v.z, a.z); a.w = fmaf(s, v.w, a.w);
    }
    *(float4*)&ctx[((size_t)c*BB + b)*H2 + h] = a;
  }
}

// ---------------- decoder input assembly --------------------------------------------------
__global__ void k_inp(const float* __restrict__ conv_seq, const float* __restrict__ ctx,
                      float* __restrict__ inp){
  int cb = blockIdx.x;
  int b = cb & 31;
  for (int k = threadIdx.x; k < 1280; k += 256){
    float v = (k < 256) ? conv_seq[b*256 + k] : ctx[(size_t)cb*H2 + (k - 256)];
    inp[(size_t)cb*1280 + k] = v;
  }
}

// ---------------- fused persistent GRU decoder: 64 WGs ------------------------------------
__global__ __launch_bounds__(256, 1) void k_dec(
    const bf16_t* __restrict__ Whp, const bf16_t* __restrict__ Ppw,
    const float* __restrict__ gi, const float* __restrict__ d_bhh,
    const float* __restrict__ seq_repr,
    const float* __restrict__ proj_b, const float* __restrict__ cls_w,
    const float* __restrict__ cls_b, bf16_t* __restrict__ hdp,
    float* __restrict__ pl, unsigned int* __restrict__ dfh,
    unsigned int* __restrict__ dfpl, float* __restrict__ out){
  const int wg = blockIdx.x;
  const int tid = threadIdx.x;
  const int wv = tid >> 6, lane = tid & 63;
  __shared__ __align__(16) bf16_t Wl[3*32*64*8];    // 98304 B
  __shared__ float red[4][32][49];                  // 25088 B
  __shared__ float plred[8][32][2];                 // 2048 B
  __shared__ float cv[2];
  {
    const uint4* src = (const uint4*)(Whp + (size_t)wg*3*32*64*8);
    uint4* dst = (uint4*)Wl;
    for (int i = tid; i < 3*32*64*8/8; i += 256) dst[i] = src[i];
  }
  const int b = tid & 31, jp = tid >> 5;
  const int j0 = wg*16 + jp*2;
  float hold[2];
  hold[0] = seq_repr[((size_t)b*SS + 127)*H2 + j0];
  hold[1] = seq_repr[((size_t)b*SS + 127)*H2 + j0 + 1];
  float bhh[3][2];
  #pragma unroll
  for (int g = 0; g < 3; ++g){
    bhh[g][0] = d_bhh[g*1024 + j0];
    bhh[g][1] = d_bhh[g*1024 + j0 + 1];
  }
  __syncthreads();
  union HU { unsigned long long u[2]; bf16x8 v; };
  const int r0 = (lane >> 4)*4, cc = lane & 15;

  for (int c = 0; c < 6; ++c){
    if (c > 0){
      const unsigned int* fp = dfh + lane*16;
      unsigned tgt = (unsigned)c;
      for(;;){
        unsigned v = ALOAD(fp);
        if (__ballot(v < tgt) == 0ull) break;
      }
    }
    f32x4 acc[2][3];
    f32x4 zero = {0.f,0.f,0.f,0.f};
    #pragma unroll
    for (int m = 0; m < 2; ++m)
      #pragma unroll
      for (int n = 0; n < 3; ++n) acc[m][n] = zero;
    const bf16_t* hb = hdp + (size_t)(c & 1)*2*32*64*8;
    #pragma unroll
    for (int i = 0; i < 8; ++i){
      int kt = wv*8 + i;
      HU u0, u1;
      const unsigned long long* p0 = (const unsigned long long*)(hb + (((size_t)0*32 + kt)*64 + lane)*8);
      const unsigned long long* p1 = (const unsigned long long*)(hb + (((size_t)1*32 + kt)*64 + lane)*8);
      u0.u[0] = ALOAD(p0);     u0.u[1] = ALOAD(p0 + 1);
      u1.u[0] = ALOAD(p1);     u1.u[1] = ALOAD(p1 + 1);
      #pragma unroll
      for (int nt = 0; nt < 3; ++nt){
        bf16x8 Bf = *reinterpret_cast<const bf16x8*>(&Wl[(((size_t)nt*32 + kt)*64 + lane)*8]);
        acc[0][nt] = __builtin_amdgcn_mfma_f32_16x16x32_bf16(u0.v, Bf, acc[0][nt], 0, 0, 0);
        acc[1][nt] = __builtin_amdgcn_mfma_f32_16x16x32_bf16(u1.v, Bf, acc[1][nt], 0, 0, 0);
      }
    }
    #pragma unroll
    for (int m = 0; m < 2; ++m)
      #pragma unroll
      for (int n = 0; n < 3; ++n)
        #pragma unroll
        for (int e = 0; e < 4; ++e)
          red[wv][m*16 + r0 + e][n*16 + cc] = acc[m][n][e];
    __syncthreads();
    float hnew[2];
    #pragma unroll
    for (int u2 = 0; u2 < 2; ++u2){
      int jj = jp*2 + u2;
      float r_ = 0.f, z_ = 0.f, n_ = 0.f;
      #pragma unroll
      for (int w = 0; w < 4; ++w){
        r_ += red[w][b][jj]; z_ += red[w][b][16+jj]; n_ += red[w][b][32+jj];
      }
      const float* gr = gi + ((size_t)(c*BB) + b)*G6 + wg*16 + jj;
      float rr = sigm(gr[0]    + bhh[0][u2] + r_);
      float zz = sigm(gr[1024] + bhh[1][u2] + z_);
      float nn = tanhf(gr[2048] + rr*(bhh[2][u2] + n_));
      hnew[u2] = tanhf((1.f - zz)*nn + zz*hold[u2]);
      hold[u2] = hnew[u2];
    }
    {
      int kt = j0 >> 5, ln = (b & 15) + 16*((j0 >> 3) & 3), rg = j0 & 7, mt = b >> 4;
      unsigned pk = (unsigned)__builtin_bit_cast(unsigned short, (bf16_t)hnew[0])
                  | ((unsigned)__builtin_bit_cast(unsigned short, (bf16_t)hnew[1]) << 16);
      unsigned* dst = (unsigned*)(hdp + (size_t)((c+1)&1)*2*32*64*8 +
                                  (((size_t)(mt*32 + kt)*64 + ln)*8 + rg));
      ASTORE(dst, pk);
    }
    __syncthreads();
    if (tid == 0)
      ASTORE(dfh + wg*16, (unsigned)(c+1));
    if (wg < 16){
      {
        const unsigned int* fp = dfh + lane*16;
        unsigned tgt = (unsigned)(c+1);
        for(;;){
          unsigned v = ALOAD(fp);
          if (__ballot(v < tgt) == 0ull) break;
        }
      }
      f32x4 pacc[2] = {zero, zero};
      const bf16_t* hb2 = hdp + (size_t)((c+1)&1)*2*32*64*8;
      #pragma unroll
      for (int i = 0; i < 8; ++i){
        int kt = wv*8 + i;
        HU u0, u1;
        const unsigned long long* p0 = (const unsigned long long*)(hb2 + (((size_t)0*32 + kt)*64 + lane)*8);
        const unsigned long long* p1 = (const unsigned long long*)(hb2 + (((size_t)1*32 + kt)*64 + lane)*8);
        u0.u[0] = ALOAD(p0);     u0.u[1] = ALOAD(p0 + 1);
        u1.u[0] = ALOAD(p1);     u1.u[1] = ALOAD(p1 + 1);
        bf16x8 Bf = *reinterpret_cast<const bf16x8*>(Ppw + (((size_t)wg*32 + kt)*64 + lane)*8);
        pacc[0] = __builtin_amdgcn_mfma_f32_16x16x32_bf16(u0.v, Bf, pacc[0], 0, 0, 0);
        pacc[1] = __builtin_amdgcn_mfma_f32_16x16x32_bf16(u1.v, Bf, pacc[1], 0, 0, 0);
      }
      #pragma unroll
      for (int m = 0; m < 2; ++m)
        #pragma unroll
        for (int e = 0; e < 4; ++e)
          red[wv][m*16 + r0 + e][cc] = pacc[m][e];
      __syncthreads();
      {
        int colp = tid >> 5;
        float v0 = 0.f, v1 = 0.f;
        #pragma unroll
        for (int w = 0; w < 4; ++w){
          v0 += red[w][b][colp*2];
          v1 += red[w][b][colp*2+1];
        }
        int c0 = wg*16 + colp*2, c1 = c0 + 1;
        plred[colp][b][0] = v0*cls_w[c0]      + v1*cls_w[c1];
        plred[colp][b][1] = v0*cls_w[PP + c0] + v1*cls_w[PP + c1];
      }
      __syncthreads();
      if (tid < 32){
        float s0 = 0.f, s1 = 0.f;
        #pragma unroll
        for (int g = 0; g < 8; ++g){ s0 += plred[g][tid][0]; s1 += plred[g][tid][1]; }
        unsigned* dp = (unsigned*)(pl + (((size_t)c*16 + wg)*32 + tid)*2);
        ASTORE(dp,     __builtin_bit_cast(unsigned, s0));
        ASTORE(dp + 1, __builtin_bit_cast(unsigned, s1));
      }
      __syncthreads();
      if (tid == 0)
        ASTORE(dfpl + wg*16, (unsigned)(c+1));
    }
  }
  if (wg == 0){
    if (lane < 16){
      const unsigned int* fp = dfpl + lane*16;
      for(;;){
        unsigned v = ALOAD(fp);
        if (__ballot(v < 6u) == 0ull) break;
      }
    }
    __syncthreads();
    float* cr = (float*)red;
    cr[tid*2]   = proj_b[tid]*cls_w[tid];
    cr[tid*2+1] = proj_b[tid]*cls_w[PP + tid];
    __syncthreads();
    if (tid < 2){
      float s = 0.f;
      for (int i = 0; i < 256; ++i) s += cr[i*2 + tid];
      cv[tid] = s;
    }
    __syncthreads();
    if (tid < 32){
      for (int c = 0; c < 6; ++c){
        float a0 = cv[0] + cls_b[0], a1 = cv[1] + cls_b[1];
        for (int w = 0; w < 16; ++w){
          const unsigned* dp = (const unsigned*)(pl + (((size_t)c*16 + w)*32 + tid)*2);
          a0 += __builtin_bit_cast(float, ALOAD(dp));
          a1 += __builtin_bit_cast(float, ALOAD(dp + 1));
        }
        float mx = fmaxf(a0, a1);
        float ls = mx + logf(expf(a0 - mx) + expf(a1 - mx));
        out[((size_t)c*BB + tid)*2 + 0] = a0 - ls;
        out[((size_t)c*BB + tid)*2 + 1] = a1 - ls;
      }
    }
  }
}

// ================================= host ===================================================
extern "C" void kernel_launch(void* const* d_in, const int* in_sizes, int n_in,
                              void* d_out, int out_size, void* d_ws, size_t ws_size,
                              hipStream_t stream){
  const int*   seq          = (const int*)  d_in[0];
  const int*   seq_char     = (const int*)  d_in[1];
  const int*   classes      = (const int*)  d_in[2];
  const float* embed_w      = (const float*)d_in[3];
  const float* char_embed_w = (const float*)d_in[4];
  const float* class_embed_w= (const float*)d_in[5];
  const float* char_conv_w  = (const float*)d_in[6];
  const float* char_conv_b  = (const float*)d_in[7];
  const float* word_conv_w  = (const float*)d_in[8];
  const float* word_conv_b  = (const float*)d_in[9];
  const float* f_Wih = (const float*)d_in[10];
  const float* f_Whh = (const float*)d_in[11];
  const float* f_b   = (const float*)d_in[12];
  const float* b_Wih = (const float*)d_in[13];
  const float* b_Whh = (const float*)d_in[14];
  const float* b_b   = (const float*)d_in[15];
  const float* attend = (const float*)d_in[16];
  const float* d_Wih  = (const float*)d_in[17];
  const float* d_Whh  = (const float*)d_in[18];
  const float* d_bih  = (const float*)d_in[19];
  const float* d_bhh  = (const float*)d_in[20];
  const float* proj_w = (const float*)d_in[21];
  const float* proj_b = (const float*)d_in[22];
  const float* cls_w  = (const float*)d_in[23];
  const float* cls_b  = (const float*)d_in[24];
  float* out = (float*)d_out;

  char* wsb = (char*)d_ws;
  size_t off = 0;
  auto alloc = [&](size_t bytes) -> char* {
    char* p = wsb + off;
    off += (bytes + 255) & ~(size_t)255;
    return p;
  };
  // --- zeroed region (contiguous from d_ws start): flags | hp ---
  unsigned int* flags = (unsigned int*)alloc(16384);   // lf@0 (2048 dw) | dfh@2048 | dfpl@3072
  unsigned int* lf   = flags;
  unsigned int* dfh  = flags + 2048;
  unsigned int* dfpl = flags + 3072;
  bf16_t* hp  = (bf16_t*)alloc((size_t)2*2*2*16*64*8 * 2);         // 128 KB (zeroed)
  const int ZERO_DWORDS = 4096 + 32768;                            // 36864
  bf16_t* hdp = (bf16_t*)alloc((size_t)2*2*32*64*8 * 2);           // 128 KB
  bf16_t* Wp2 = (bf16_t*)alloc((size_t)2*64*NKT*2*64*8 * 2);       // 7.34 MB
  bf16_t* Whp = (bf16_t*)alloc((size_t)64*3*32*64*8 * 2);
  bf16_t* Ppw = (bf16_t*)alloc((size_t)16*32*64*8 * 2);
  bf16_t* xp  = (bf16_t*)alloc((size_t)128*2*NKTX*64*8 * 2);
  float* pl       = (float*)alloc((size_t)6*16*32*2*4);
  float* x        = (float*)alloc((size_t)BB*SS*EC*4);
  float* mask     = (float*)alloc((size_t)BB*SS*4);
  float* cbar     = (float*)alloc((size_t)4096*512*4);
  float* xbar     = (float*)alloc((size_t)BB*EC*64*4);
  float* conv_seq = (float*)alloc((size_t)BB*256*4);
  float* seq_repr = (float*)alloc((size_t)BB*SS*H2*4);
  float* ta       = (float*)alloc((size_t)6*H2*4);
  float* ctx      = (float*)alloc((size_t)6*BB*H2*4);
  float* inp      = (float*)alloc((size_t)192*1280*4);
  float* gi       = (float*)alloc((size_t)192*G6*4);
  float* part_char= (float*)alloc((size_t)2*4096*64*4);
  float* part_word= (float*)alloc((size_t)32*BB*256*4);
  float* part_gi  = (float*)alloc((size_t)4*192*G6*4);
  (void)ws_size; (void)in_sizes; (void)n_in; (void)out_size;

  k_zero<<<(ZERO_DWORDS + 255)/256, 256, 0, stream>>>((unsigned int*)d_ws, ZERO_DWORDS);

  k_packw2<<<2*64*NKT, 64, 0, stream>>>(f_Wih, f_Whh, b_Wih, b_Whh, Wp2);
  k_packdw<<<64*3*32, 64, 0, stream>>>(d_Whh, Whp);
  k_packpw<<<16*32, 64, 0, stream>>>(proj_w, Ppw);
  k_embed<<<BB*SS, 256, 0, stream>>>(seq, embed_w, x, mask);
  k_cbar<<<BB*SS, 64, 0, stream>>>(seq_char, char_embed_w, cbar);
  k_gemm<32,64,2,4><<<dim3(128,1,2), 256, 0, stream>>>(cbar, char_conv_w, part_char, 4096, 64, 512, 256);
  k_fin<<<dim3(1,4096), 64, 0, stream>>>(part_char, char_conv_b, x + 256, 4096, 64, 2, EC, 1);
  k_xbar<<<160, 64, 0, stream>>>(x, xbar);
  k_gemm<32,64,2,4><<<dim3(1,4,32), 256, 0, stream>>>(xbar, word_conv_w, part_word, 32, 256, 20480, 640);
  k_fin<<<dim3(4,32), 64, 0, stream>>>(part_word, word_conv_b, conv_seq, 32, 256, 32, 256, 1);
  k_packx<<<128*2*NKTX, 64, 0, stream>>>(x, xp);
  k_lstm<<<128, 64, 0, stream>>>(Wp2, xp, hp, f_b, b_b, seq_repr, lf);
  k_ta<<<6, 256, 0, stream>>>(classes, class_embed_w, attend, ta);
  k_ctx<<<dim3(6,32), 256, 0, stream>>>(ta, seq_repr, mask, ctx);
  k_inp<<<192, 256, 0, stream>>>(conv_seq, ctx, inp);
  k_gemm<64,64,4,4><<<dim3(3,48,4), 256, 0, stream>>>(inp, d_Wih, part_gi, 192, G6, 1280, 320);
  k_fin<<<dim3(48,192), 64, 0, stream>>>(part_gi, d_bih, gi, 192, G6, 4, G6, 0);
  k_hprep<<<64, 64, 0, stream>>>(seq_repr, hdp);
  k_dec<<<64, 256, 0, stream>>>(Whp, Ppw, gi, d_bhh, seq_repr, proj_b, cls_w, cls_b,
                                hdp, pl, dfh, dfpl, out);
}

// Round 9
// 646.693 us; speedup vs baseline: 1.5577x; 1.5577x over previous
//
#include <hip/hip_runtime.h>

typedef __bf16 bf16_t;
typedef __bf16 bf16x8 __attribute__((ext_vector_type(8)));
typedef float f32x4 __attribute__((ext_vector_type(4)));
typedef unsigned u32x4 __attribute__((ext_vector_type(4)));
typedef unsigned long long u64;

static constexpr int BB = 32, SS = 128, WW = 16, EE = 256, CDm = 64, HH = 512, PP = 256;
static constexpr int EC = 320;    // E + CD
static constexpr int H2 = 1024;   // 2H
static constexpr int G6 = 3072;   // 6H
static constexpr int NKT = 28;    // 16 h-ktiles + 12 x-ktiles (x padded 320->384)
static constexpr int NKTX = 12;

__device__ __forceinline__ float sigm(float x){ return 1.f/(1.f + expf(-x)); }

#define ALOAD(p)    __hip_atomic_load((p),  __ATOMIC_RELAXED, __HIP_MEMORY_SCOPE_AGENT)
#define ASTORE(p,v) __hip_atomic_store((p),(v),__ATOMIC_RELAXED, __HIP_MEMORY_SCOPE_AGENT)

// ---- dual-mode memory ops: LLC=true -> sc0 sc1 (device coherence point);
// ----                       LLC=false -> sc0 only (XCD-local L2, same-XCD coherent)
template<bool LLC>
__device__ __forceinline__ unsigned ld_flag(const unsigned* p){
  unsigned r;
  if constexpr (LLC)
    asm volatile("global_load_dword %0, %1, off sc0 sc1\n\ts_waitcnt vmcnt(0)"
                 : "=&v"(r) : "v"(p) : "memory");
  else
    asm volatile("global_load_dword %0, %1, off sc0\n\ts_waitcnt vmcnt(0)"
                 : "=&v"(r) : "v"(p) : "memory");
  return r;
}
template<bool LLC>
__device__ __forceinline__ void ld16(u32x4& d, const void* p){
  if constexpr (LLC)
    asm volatile("global_load_dwordx4 %0, %1, off sc0 sc1" : "=&v"(d) : "v"(p) : "memory");
  else
    asm volatile("global_load_dwordx4 %0, %1, off sc0"     : "=&v"(d) : "v"(p) : "memory");
}
template<bool LLC>
__device__ __forceinline__ void st32(unsigned* p, unsigned v){
  if constexpr (LLC)
    asm volatile("global_store_dword %0, %1, off sc0 sc1" :: "v"(p), "v"(v) : "memory");
  else
    asm volatile("global_store_dword %0, %1, off sc0"     :: "v"(p), "v"(v) : "memory");
}
__device__ __forceinline__ void vm_drain(){
  asm volatile("s_waitcnt vmcnt(0)" ::: "memory");
  __builtin_amdgcn_sched_barrier(0);
}

// ---------------- embedding + char means (fused; NEW this round) --------------------------
__global__ void k_embed_cbar(const int* __restrict__ seq, const float* __restrict__ embed_w,
                             const int* __restrict__ seq_char, const float* __restrict__ cemb,
                             float* __restrict__ x, float* __restrict__ mask,
                             float* __restrict__ cbar){
  int bs = blockIdx.x; int tid = threadIdx.x;
  int wid = seq[bs];
  x[(size_t)bs*EC + tid] = tanhf(embed_w[(size_t)wid*EE + tid]);
  if (tid == 0) mask[bs] = (wid > 0) ? 1.f : 0.f;
  if (tid < 64){
    int c = tid;
    float ce[WW];
    #pragma unroll
    for (int p = 0; p < WW; ++p){
      int id = seq_char[bs*WW + p];
      ce[p] = cemb[(size_t)id*CDm + c];
    }
    #pragma unroll
    for (int k = 0; k < 8; ++k){
      float s = 0.f;
      #pragma unroll
      for (int p = 0; p < 9; ++p) s += ce[k+p];
      cbar[(size_t)bs*512 + c*8 + k] = s * (1.f/9.f);
    }
  }
}

// ---------------- x sliding means ---------------------------------------------------------
__global__ __launch_bounds__(64) void k_xbar(const float* __restrict__ x, float* __restrict__ xbar){
  __shared__ float xl[64][129];
  int gid = blockIdx.x*64 + threadIdx.x;  // 0..10239
  int b = gid / EC, c = gid % EC;
  int tl = threadIdx.x;
  for (int t = 0; t < SS; ++t) xl[tl][t] = x[((size_t)b*SS + t)*EC + c];
  float s = 0.f;
  for (int t = 0; t < 65; ++t) s += xl[tl][t];
  const float inv = 1.f/65.f;
  float* o = &xbar[(size_t)(b*EC + c)*64];
  o[0] = s*inv;
  for (int k = 1; k < 64; ++k){ s += xl[tl][k+64] - xl[tl][k-1]; o[k] = s*inv; }
}

// ---------------- generic fp32 tiled GEMM -------------------------------------------------
template<int BM,int BN,int TM,int TN>
__global__ __launch_bounds__(256) void k_gemm(const float* __restrict__ A,
    const float* __restrict__ Wm, float* __restrict__ part,
    int M, int N, int K, int kslice){
  __shared__ float As[32][BM+4];
  __shared__ float Ws[32][BN+4];
  const int tid = threadIdx.x;
  const int tx = tid & 15, ty = tid >> 4;
  const int m0 = blockIdx.x*BM, n0 = blockIdx.y*BN, ks = blockIdx.z;
  const int kb = ks*kslice;
  float acc[TM][TN];
  #pragma unroll
  for (int i = 0; i < TM; ++i)
    #pragma unroll
    for (int j = 0; j < TN; ++j) acc[i][j] = 0.f;
  for (int kt = 0; kt < kslice; kt += 32){
    constexpr int AIT = (BM*8)/256;
    #pragma unroll
    for (int it = 0; it < AIT; ++it){
      int ch = tid + it*256;
      int r = ch >> 3, kc = (ch & 7)*4;
      float4 v = *(const float4*)(A + (size_t)(m0+r)*K + kb + kt + kc);
      As[kc+0][r]=v.x; As[kc+1][r]=v.y; As[kc+2][r]=v.z; As[kc+3][r]=v.w;
    }
    constexpr int WIT = (BN*8)/256;
    #pragma unroll
    for (int it = 0; it < WIT; ++it){
      int ch = tid + it*256;
      int r = ch >> 3, kc = (ch & 7)*4;
      float4 v = *(const float4*)(Wm + (size_t)(n0+r)*K + kb + kt + kc);
      Ws[kc+0][r]=v.x; Ws[kc+1][r]=v.y; Ws[kc+2][r]=v.z; Ws[kc+3][r]=v.w;
    }
    __syncthreads();
    #pragma unroll
    for (int kk = 0; kk < 32; ++kk){
      float a[TM], wv[TN];
      #pragma unroll
      for (int i = 0; i < TM; ++i) a[i] = As[kk][ty*TM+i];
      #pragma unroll
      for (int j = 0; j < TN; ++j) wv[j] = Ws[kk][tx*TN+j];
      #pragma unroll
      for (int i = 0; i < TM; ++i)
        #pragma unroll
        for (int j = 0; j < TN; ++j) acc[i][j] = fmaf(a[i], wv[j], acc[i][j]);
    }
    __syncthreads();
  }
  #pragma unroll
  for (int i = 0; i < TM; ++i){
    int row = m0 + ty*TM + i;
    #pragma unroll
    for (int j = 0; j < TN; ++j){
      int col = n0 + tx*TN + j;
      part[((size_t)ks*M + row)*N + col] = acc[i][j];
    }
  }
}

// ---------------- char conv GEMM, fused bias+tanh -> x[:,256:320] (NEW this round) --------
__global__ __launch_bounds__(256) void k_cgemm(const float* __restrict__ A,
    const float* __restrict__ Wm, const float* __restrict__ bias, float* __restrict__ x){
  // M=4096, N=64, K=512; BM=32, full-K per block
  __shared__ float As[32][36];
  __shared__ float Ws[32][68];
  const int tid = threadIdx.x;
  const int tx = tid & 15, ty = tid >> 4;
  const int m0 = blockIdx.x*32;
  float acc[2][4];
  #pragma unroll
  for (int i = 0; i < 2; ++i)
    #pragma unroll
    for (int j = 0; j < 4; ++j) acc[i][j] = 0.f;
  for (int kt = 0; kt < 512; kt += 32){
    {
      int r = tid >> 3, kc = (tid & 7)*4;
      float4 v = *(const float4*)(A + (size_t)(m0+r)*512 + kt + kc);
      As[kc+0][r]=v.x; As[kc+1][r]=v.y; As[kc+2][r]=v.z; As[kc+3][r]=v.w;
    }
    #pragma unroll
    for (int it = 0; it < 2; ++it){
      int ch = tid + it*256;
      int r = ch >> 3, kc = (ch & 7)*4;
      float4 v = *(const float4*)(Wm + (size_t)r*512 + kt + kc);
      Ws[kc+0][r]=v.x; Ws[kc+1][r]=v.y; Ws[kc+2][r]=v.z; Ws[kc+3][r]=v.w;
    }
    __syncthreads();
    #pragma unroll
    for (int kk = 0; kk < 32; ++kk){
      float a[2], wv[4];
      a[0] = As[kk][ty*2]; a[1] = As[kk][ty*2+1];
      #pragma unroll
      for (int j = 0; j < 4; ++j) wv[j] = Ws[kk][tx*4+j];
      #pragma unroll
      for (int i = 0; i < 2; ++i)
        #pragma unroll
        for (int j = 0; j < 4; ++j) acc[i][j] = fmaf(a[i], wv[j], acc[i][j]);
    }
    __syncthreads();
  }
  #pragma unroll
  for (int i = 0; i < 2; ++i){
    int row = m0 + ty*2 + i;
    #pragma unroll
    for (int j = 0; j < 4; ++j){
      int col = tx*4 + j;
      x[(size_t)row*EC + 256 + col] = tanhf(acc[i][j] + bias[col]);
    }
  }
}

// ---------------- finalize partials -------------------------------------------------------
__global__ __launch_bounds__(64) void k_fin(const float* __restrict__ part,
    const float* __restrict__ bias, float* __restrict__ out,
    int M, int N, int KS, int ldc, int act){
  int col = blockIdx.x*64 + threadIdx.x;
  int row = blockIdx.y;
  float v = bias ? bias[col] : 0.f;
  for (int ks = 0; ks < KS; ++ks) v += part[((size_t)ks*M + row)*N + col];
  if (act) v = tanhf(v);
  out[(size_t)row*ldc + col] = v;
}

// ---------------- pack LSTM weights into B-fragment order ---------------------------------
__global__ __launch_bounds__(64) void k_packw(const float* __restrict__ fWih, const float* __restrict__ fWhh,
    const float* __restrict__ bWih, const float* __restrict__ bWhh, bf16_t* __restrict__ Wp){
  int id = blockIdx.x;
  int kt = id % NKT; id /= NKT;
  int slice = id % 32; int dir = id / 32;
  int l = threadIdx.x;
  const float* Whh = dir ? bWhh : fWhh;
  const float* Wih = dir ? bWih : fWih;
  int krow = (l >> 4)*8;
  for (int nt = 0; nt < 4; ++nt){
    int row = nt*512 + slice*16 + (l & 15);
    bf16_t* dst = &Wp[((((size_t)(dir*32+slice)*NKT + kt)*4 + nt)*64 + l)*8];
    if (kt < 16){
      const float* src = &Whh[(size_t)row*512 + kt*32 + krow];
      #pragma unroll
      for (int r = 0; r < 8; ++r) dst[r] = (bf16_t)src[r];
    } else {
      int kx = (kt-16)*32 + krow;
      if (kx + 8 <= 320){
        const float* src = &Wih[(size_t)row*320 + kx];
        #pragma unroll
        for (int r = 0; r < 8; ++r) dst[r] = (bf16_t)src[r];
      } else {
        #pragma unroll
        for (int r = 0; r < 8; ++r) dst[r] = (bf16_t)0.f;
      }
    }
  }
}

// ---------------- pack decoder Whh: Whp[wg(64)][nt(3)][kt(32)][lane][8] -------------------
__global__ __launch_bounds__(64) void k_packdw(const float* __restrict__ W, bf16_t* __restrict__ Wo){
  int id = blockIdx.x;               // 64*3*32
  int kt = id % 32; id /= 32;
  int nt = id % 3;  int wg = id / 3;
  int l = threadIdx.x;
  int col = nt*1024 + wg*16 + (l & 15);
  int k0 = kt*32 + (l >> 4)*8;
  bf16_t* dst = Wo + (((size_t)(wg*3 + nt)*32 + kt)*64 + l)*8;
  const float* src = W + (size_t)col*1024 + k0;
  #pragma unroll
  for (int r = 0; r < 8; ++r) dst[r] = (bf16_t)src[r];
}

// ---------------- pack proj_w: Ppw[wg(16)][kt(32)][lane][8] -------------------------------
__global__ __launch_bounds__(64) void k_packpw(const float* __restrict__ W, bf16_t* __restrict__ Wo){
  int id = blockIdx.x;               // 16*32
  int kt = id & 31, wg = id >> 5;
  int l = threadIdx.x;
  int col = wg*16 + (l & 15);
  int k0 = kt*32 + (l >> 4)*8;
  bf16_t* dst = Wo + (((size_t)wg*32 + kt)*64 + l)*8;
  const float* src = W + (size_t)col*1024 + k0;
  #pragma unroll
  for (int r = 0; r < 8; ++r) dst[r] = (bf16_t)src[r];
}

// ---------------- pack x into A-fragment order --------------------------------------------
__global__ __launch_bounds__(64) void k_packx(const float* __restrict__ x, bf16_t* __restrict__ xp){
  int id = blockIdx.x;
  int ktx = id % NKTX; id /= NKTX;
  int mt = id & 1; int t = id >> 1;        // 0..127
  int l = threadIdx.x;
  int b = (l & 15) + 16*mt;
  int c = ktx*32 + (l >> 4)*8;
  bf16_t* dst = &xp[(((size_t)t*2 + mt)*NKTX + ktx)*64*8 + (size_t)l*8];
  if (c + 8 <= EC){
    const float* src = &x[((size_t)b*SS + t)*EC + c];
    #pragma unroll
    for (int r = 0; r < 8; ++r) dst[r] = (bf16_t)src[r];
  } else {
    #pragma unroll
    for (int r = 0; r < 8; ++r) dst[r] = (bf16_t)0.f;
  }
}

// ---------------- zero control region through the coherence point -------------------------
__global__ __launch_bounds__(256) void k_zero(unsigned int* __restrict__ base, int n){
  int i = blockIdx.x*256 + threadIdx.x;
  if (i < n) ASTORE(base + i, 0u);
}

// ---------------- pack decoder h0 ---------------------------------------------------------
__global__ __launch_bounds__(64) void k_hprep(const float* __restrict__ seq_repr,
                                              bf16_t* __restrict__ hdp){
  int mt = blockIdx.x >> 5, kt = blockIdx.x & 31, l = threadIdx.x;
  int b = mt*16 + (l & 15);
  int jb = kt*32 + (l >> 4)*8;
  const float* src = &seq_repr[((size_t)b*SS + 127)*H2 + jb];
  unsigned* dst = (unsigned*)(hdp + (((size_t)mt*32 + kt)*64 + l)*8);
  #pragma unroll
  for (int p = 0; p < 4; ++p){
    unsigned pk = (unsigned)__builtin_bit_cast(unsigned short, (bf16_t)src[2*p])
                | ((unsigned)__builtin_bit_cast(unsigned short, (bf16_t)src[2*p+1]) << 16);
    ASTORE(dst + p, pk);
  }
}

// ---------------- BiLSTM step-loop body, dual-mode (R4-submission verbatim) ----------------
template<bool LLC>
__device__ void lstm_body(const bf16_t* __restrict__ Wp, const bf16_t* __restrict__ xp,
    bf16_t* __restrict__ hp, const float* __restrict__ fb, const float* __restrict__ bb,
    float* __restrict__ seq_repr, unsigned* __restrict__ lf,
    int dir, int slice, int tid, bf16_t* Wl, float (*red)[32][65],
    float* bias_l, float (*c_l)[32]){
  const int wv = tid >> 6, lane = tid & 63;
  {
    const uint4* src = (const uint4*)(Wp + ((size_t)(dir*32 + slice))*NKT*4*64*8);
    uint4* dst = (uint4*)Wl;
    for (int i = tid; i < NKT*4*64*8/8; i += 256) dst[i] = src[i];
  }
  if (tid < 64){
    const float* bv = dir ? bb : fb;
    bias_l[tid] = bv[(tid >> 4)*512 + slice*16 + (tid & 15)];
  }
  ((float*)c_l)[tid]       = 0.f;
  ((float*)c_l)[tid + 256] = 0.f;
  __syncthreads();

  for (int t = 0; t < SS; ++t){
    const int ph = t & 1;
    const int s = dir ? ((SS - t) & 127) : t;
    f32x4 acc[2][4];
    f32x4 zero = {0.f,0.f,0.f,0.f};
    #pragma unroll
    for (int m = 0; m < 2; ++m)
      #pragma unroll
      for (int n = 0; n < 4; ++n) acc[m][n] = zero;

    // ---- x loads + x MFMAs (overlap the poll below) ------------------------------------
    const bf16_t* xb = xp + (size_t)s*2*NKTX*64*8;
    bf16x8 ax[3][2];
    #pragma unroll
    for (int i = 0; i < 3; ++i){
      int ktx = wv*3 + i;
      #pragma unroll
      for (int m = 0; m < 2; ++m)
        ax[i][m] = *reinterpret_cast<const bf16x8*>(xb + (((size_t)m*NKTX + ktx)*64 + lane)*8);
    }
    #pragma unroll
    for (int i = 0; i < 3; ++i){
      int kt = 16 + wv*3 + i;
      #pragma unroll
      for (int nt = 0; nt < 4; ++nt){
        bf16x8 Bf = *reinterpret_cast<const bf16x8*>(&Wl[(((size_t)kt*4 + nt)*64 + lane)*8]);
        acc[0][nt] = __builtin_amdgcn_mfma_f32_16x16x32_bf16(ax[i][0], Bf, acc[0][nt], 0, 0, 0);
        acc[1][nt] = __builtin_amdgcn_mfma_f32_16x16x32_bf16(ax[i][1], Bf, acc[1][nt], 0, 0, 0);
      }
    }
    // ---- per-wave poll: only this wave's 8 producers -----------------------------------
    if (t > 0 && lane < 8){
      int prod = dir*32 + (wv + 4*(lane >> 1))*2 + (lane & 1);
      const unsigned* fp = lf + prod*16;
      unsigned tgt = (unsigned)t;
      for(;;){
        unsigned v = ld_flag<LLC>(fp);
        if (__ballot(v < tgt) == 0ull) break;
      }
    }
    // ---- h fragment loads + MFMAs ------------------------------------------------------
    const bf16_t* hb_ = hp + ((size_t)(ph*2 + dir))*2*16*64*8;
    u32x4 hr[4][2];
    #pragma unroll
    for (int i = 0; i < 4; ++i){
      int kt = wv + 4*i;
      #pragma unroll
      for (int m = 0; m < 2; ++m)
        ld16<LLC>(hr[i][m], hb_ + (((size_t)m*16 + kt)*64 + lane)*8);
    }
    vm_drain();
    #pragma unroll
    for (int i = 0; i < 4; ++i){
      int kt = wv + 4*i;
      bf16x8 a0 = __builtin_bit_cast(bf16x8, hr[i][0]);
      bf16x8 a1 = __builtin_bit_cast(bf16x8, hr[i][1]);
      #pragma unroll
      for (int nt = 0; nt < 4; ++nt){
        bf16x8 Bf = *reinterpret_cast<const bf16x8*>(&Wl[(((size_t)kt*4 + nt)*64 + lane)*8]);
        acc[0][nt] = __builtin_amdgcn_mfma_f32_16x16x32_bf16(a0, Bf, acc[0][nt], 0, 0, 0);
        acc[1][nt] = __builtin_amdgcn_mfma_f32_16x16x32_bf16(a1, Bf, acc[1][nt], 0, 0, 0);
      }
    }
    // ---- cross-wave K-reduction --------------------------------------------------------
    {
      int r0 = (lane >> 4)*4, cc = lane & 15;
      #pragma unroll
      for (int m = 0; m < 2; ++m)
        #pragma unroll
        for (int n = 0; n < 4; ++n)
          #pragma unroll
          for (int e = 0; e < 4; ++e)
            red[wv][m*16 + r0 + e][n*16 + cc] = acc[m][n][e];
    }
    __syncthreads();
    // ---- gates + state update ----------------------------------------------------------
    {
      int b = tid & 31, jjp = tid >> 5;
      float hv[2];
      #pragma unroll
      for (int u2 = 0; u2 < 2; ++u2){
        int jj = jjp*2 + u2;
        float gi_ = bias_l[jj],     gf_ = bias_l[16+jj];
        float gg_ = bias_l[32+jj],  go_ = bias_l[48+jj];
        #pragma unroll
        for (int w2 = 0; w2 < 4; ++w2){
          gi_ += red[w2][b][jj];      gf_ += red[w2][b][16+jj];
          gg_ += red[w2][b][32+jj];   go_ += red[w2][b][48+jj];
        }
        float ii = sigm(gi_), ff = sigm(gf_), g2 = tanhf(gg_), oo = sigm(go_);
        float c = ff*c_l[jj][b] + ii*g2;
        c_l[jj][b] = c;
        hv[u2] = oo*tanhf(c);
      }
      int j0 = slice*16 + jjp*2;
      int s_out = dir ? (127 - t) : t;
      float2 st; st.x = hv[0]; st.y = hv[1];
      *(float2*)&seq_repr[((size_t)b*SS + s_out)*H2 + dir*HH + j0] = st;
      int mt = b >> 4, kth = j0 >> 5, ln = (b & 15) + 16*((j0 >> 3) & 3), rg = j0 & 7;
      unsigned pk = (unsigned)__builtin_bit_cast(unsigned short, (bf16_t)hv[0])
                  | ((unsigned)__builtin_bit_cast(unsigned short, (bf16_t)hv[1]) << 16);
      unsigned* dst = (unsigned*)(hp +
          ((((size_t)((ph^1)*2 + dir)*2 + mt)*16 + kth)*64 + ln)*8 + rg);
      st32<LLC>(dst, pk);
    }
    // drain own h store, join, then publish flag
    asm volatile("s_waitcnt vmcnt(0)" ::: "memory");
    __syncthreads();
    if (tid == 0)
      st32<LLC>(lf + (dir*32 + slice)*16, (unsigned)(t+1));
  }
}

// ---------------- persistent BiLSTM with runtime XCD-placement detection ------------------
__global__ __launch_bounds__(256, 1) void k_lstm(const bf16_t* __restrict__ Wp,
    const bf16_t* __restrict__ xp, bf16_t* __restrict__ hp,
    const float* __restrict__ fb, const float* __restrict__ bb,
    float* __restrict__ seq_repr, unsigned* __restrict__ lf,
    unsigned* __restrict__ xcc_tab, unsigned* __restrict__ modep){
  const int blk = blockIdx.x;
  const int tid = threadIdx.x;
  __shared__ __align__(16) bf16_t Wl[NKT*4*64*8];   // 114688 B
  __shared__ float red[4][32][65];
  __shared__ float bias_l[64];
  __shared__ float c_l[16][32];
  __shared__ unsigned mode_s;

  unsigned xcc;
  asm volatile("s_getreg_b32 %0, hwreg(HW_REG_XCC_ID)" : "=s"(xcc));
  if (tid == 0) ASTORE(xcc_tab + blk, xcc + 1u);
  if (blk == 0){
    unsigned* tabl = (unsigned*)red;
    unsigned v = 0; int spins = 0;
    for (;;){
      v = ALOAD(xcc_tab + tid);
      if (v != 0u || spins >= 200000) break;
      ++spins; __builtin_amdgcn_s_sleep(2);
    }
    tabl[tid] = v;
    __syncthreads();
    if (tid == 0){
      unsigned mode = 1;
      unsigned c0 = tabl[0], c1 = tabl[1];
      if (c0 == 0u || c1 == 0u) mode = 2;
      for (int k = 0; k < 32; ++k)
        if (tabl[8*k] != c0 || tabl[8*k + 1] != c1) mode = 2;
      ASTORE(modep, mode);
      mode_s = mode;
    }
    __syncthreads();
  } else {
    if (tid == 0){
      unsigned m;
      while ((m = ALOAD(modep)) == 0u) __builtin_amdgcn_s_sleep(2);
      mode_s = m;
    }
    __syncthreads();
  }
  const unsigned mode = mode_s;
  int dir, slice; bool worker;
  if (mode == 1){ worker = (blk & 7) < 2; dir = blk & 7; slice = blk >> 3; }
  else          { worker = blk < 64;      dir = blk >> 5; slice = blk & 31; }
  if (!worker) return;
  if (mode == 1)
    lstm_body<false>(Wp, xp, hp, fb, bb, seq_repr, lf, dir, slice, tid, Wl, red, bias_l, c_l);
  else
    lstm_body<true >(Wp, xp, hp, fb, bb, seq_repr, lf, dir, slice, tid, Wl, red, bias_l, c_l);
}

// ---------------- attention ---------------------------------------------------------------
__global__ __launch_bounds__(256) void k_ta(const int* __restrict__ classes,
    const float* __restrict__ cls_emb, const float* __restrict__ attend, float* __restrict__ ta){
  int c = blockIdx.x;
  __shared__ float t2[EE];
  int tid = threadIdx.x;
  int ci = classes[c];
  t2[tid] = tanhf(tanhf(cls_emb[(size_t)ci*EE + tid]));
  __syncthreads();
  for (int r = 0; r < 4; ++r){
    int h = r*256 + tid;
    float acc = 0.f;
    for (int e = 0; e < EE; ++e) acc = fmaf(t2[e], attend[(size_t)e*H2 + h], acc);
    ta[c*H2 + h] = tanhf(acc);
  }
}

__global__ __launch_bounds__(256) void k_ctx(const float* __restrict__ ta,
    const float* __restrict__ seq_repr, const float* __restrict__ mask, float* __restrict__ ctx){
  int c = blockIdx.x, b = blockIdx.y;
  __shared__ float ta_l[H2];
  __shared__ float ps[128][2];
  __shared__ float sc[128];
  int tid = threadIdx.x;
  for (int i = tid; i < H2; i += 256) ta_l[i] = ta[c*H2 + i];
  __syncthreads();
  {
    int tt = tid >> 1, half = tid & 1;
    const float* row = &seq_repr[((size_t)b*SS + tt)*H2 + half*512];
    const float* tl = &ta_l[half*512];
    float p = 0.f;
    for (int i = 0; i < 512; i += 4){
      float4 v = *(const float4*)&row[i];
      p = fmaf(tl[i], v.x, p);   p = fmaf(tl[i+1], v.y, p);
      p = fmaf(tl[i+2], v.z, p); p = fmaf(tl[i+3], v.w, p);
    }
    ps[tt][half] = p;
  }
  __syncthreads();
  if (tid < 128){
    float s = (ps[tid][0] + ps[tid][1]) * 128.f * mask[b*SS + tid];
    sc[tid] = tanhf(s);
  }
  __syncthreads();
  {
    int h = tid*4;
    float4 a = {0.f,0.f,0.f,0.f};
    for (int t = 0; t < SS; ++t){
      float s = sc[t];
      float4 v = *(const float4*)&seq_repr[((size_t)b*SS + t)*H2 + h];
      a.x = fmaf(s, v.x, a.x); a.y = fmaf(s, v.y, a.y);
      a.z = fmaf(s, v.z, a.z); a.w = fmaf(s, v.w, a.w);
    }
    *(float4*)&ctx[((size_t)c*BB + b)*H2 + h] = a;
  }
}

// ---------------- gi GEMM: A gathered from (conv_seq | ctx) (NEW this round) --------------
__global__ __launch_bounds__(256) void k_gemmgi(const float* __restrict__ conv_seq,
    const float* __restrict__ ctx, const float* __restrict__ Wm, float* __restrict__ part){
  // M=192, N=3072, K=1280; BM=64, BN=64, TM=4, TN=4; kslice=320; grid(3,48,4)
  __shared__ float As[32][68];
  __shared__ float Ws[32][68];
  const int tid = threadIdx.x;
  const int tx = tid & 15, ty = tid >> 4;
  const int m0 = blockIdx.x*64, n0 = blockIdx.y*64, ks = blockIdx.z;
  const int kb = ks*320;
  float acc[4][4];
  #pragma unroll
  for (int i = 0; i < 4; ++i)
    #pragma unroll
    for (int j = 0; j < 4; ++j) acc[i][j] = 0.f;
  for (int kt = 0; kt < 320; kt += 32){
    #pragma unroll
    for (int it = 0; it < 2; ++it){
      int ch = tid + it*256;
      int r = ch >> 3, kc = (ch & 7)*4;
      int row = m0 + r;
      int cc2 = row >> 5, bb2 = row & 31;
      int k4 = kb + kt + kc;
      const float* ap = (k4 < 256) ? (conv_seq + bb2*256 + k4)
                                   : (ctx + ((size_t)(cc2*BB) + bb2)*H2 + (k4 - 256));
      float4 v = *(const float4*)ap;
      As[kc+0][r]=v.x; As[kc+1][r]=v.y; As[kc+2][r]=v.z; As[kc+3][r]=v.w;
    }
    #pragma unroll
    for (int it = 0; it < 2; ++it){
      int ch = tid + it*256;
      int r = ch >> 3, kc = (ch & 7)*4;
      float4 v = *(const float4*)(Wm + (size_t)(n0+r)*1280 + kb + kt + kc);
      Ws[kc+0][r]=v.x; Ws[kc+1][r]=v.y; Ws[kc+2][r]=v.z; Ws[kc+3][r]=v.w;
    }
    __syncthreads();
    #pragma unroll
    for (int kk = 0; kk < 32; ++kk){
      float a[4], wv[4];
      #pragma unroll
      for (int i = 0; i < 4; ++i) a[i] = As[kk][ty*4+i];
      #pragma unroll
      for (int j = 0; j < 4; ++j) wv[j] = Ws[kk][tx*4+j];
      #pragma unroll
      for (int i = 0; i < 4; ++i)
        #pragma unroll
        for (int j = 0; j < 4; ++j) acc[i][j] = fmaf(a[i], wv[j], acc[i][j]);
    }
    __syncthreads();
  }
  #pragma unroll
  for (int i = 0; i < 4; ++i){
    int row = m0 + ty*4 + i;
    #pragma unroll
    for (int j = 0; j < 4; ++j){
      int col = n0 + tx*4 + j;
      part[((size_t)ks*192 + row)*G6 + col] = acc[i][j];
    }
  }
}

// ---------------- fused persistent GRU decoder: 64 WGs (R4-submission verbatim) -----------
__global__ __launch_bounds__(256, 1) void k_dec(
    const bf16_t* __restrict__ Whp, const bf16_t* __restrict__ Ppw,
    const float* __restrict__ gi, const float* __restrict__ d_bhh,
    const float* __restrict__ seq_repr,
    const float* __restrict__ proj_b, const float* __restrict__ cls_w,
    const float* __restrict__ cls_b, bf16_t* __restrict__ hdp,
    float* __restrict__ pl, unsigned int* __restrict__ dfh,
    unsigned int* __restrict__ dfpl, float* __restrict__ out){
  const int wg = blockIdx.x;
  const int tid = threadIdx.x;
  const int wv = tid >> 6, lane = tid & 63;
  __shared__ __align__(16) bf16_t Wl[3*32*64*8];    // 98304 B
  __shared__ float red[4][32][49];                  // 25088 B
  __shared__ float plred[8][32][2];                 // 2048 B
  __shared__ float cv[2];
  {
    const uint4* src = (const uint4*)(Whp + (size_t)wg*3*32*64*8);
    uint4* dst = (uint4*)Wl;
    for (int i = tid; i < 3*32*64*8/8; i += 256) dst[i] = src[i];
  }
  const int b = tid & 31, jp = tid >> 5;
  const int j0 = wg*16 + jp*2;
  float hold[2];
  hold[0] = seq_repr[((size_t)b*SS + 127)*H2 + j0];
  hold[1] = seq_repr[((size_t)b*SS + 127)*H2 + j0 + 1];
  float bhh[3][2];
  #pragma unroll
  for (int g = 0; g < 3; ++g){
    bhh[g][0] = d_bhh[g*1024 + j0];
    bhh[g][1] = d_bhh[g*1024 + j0 + 1];
  }
  __syncthreads();
  union HU { unsigned long long u[2]; bf16x8 v; };
  const int r0 = (lane >> 4)*4, cc = lane & 15;

  for (int c = 0; c < 6; ++c){
    if (c > 0){
      const unsigned int* fp = dfh + lane*16;
      unsigned tgt = (unsigned)c;
      for(;;){
        unsigned v = ALOAD(fp);
        if (__ballot(v < tgt) == 0ull) break;
      }
    }
    f32x4 acc[2][3];
    f32x4 zero = {0.f,0.f,0.f,0.f};
    #pragma unroll
    for (int m = 0; m < 2; ++m)
      #pragma unroll
      for (int n = 0; n < 3; ++n) acc[m][n] = zero;
    const bf16_t* hb = hdp + (size_t)(c & 1)*2*32*64*8;
    #pragma unroll
    for (int i = 0; i < 8; ++i){
      int kt = wv*8 + i;
      HU u0, u1;
      const unsigned long long* p0 = (const unsigned long long*)(hb + (((size_t)0*32 + kt)*64 + lane)*8);
      const unsigned long long* p1 = (const unsigned long long*)(hb + (((size_t)1*32 + kt)*64 + lane)*8);
      u0.u[0] = ALOAD(p0);     u0.u[1] = ALOAD(p0 + 1);
      u1.u[0] = ALOAD(p1);     u1.u[1] = ALOAD(p1 + 1);
      #pragma unroll
      for (int nt = 0; nt < 3; ++nt){
        bf16x8 Bf = *reinterpret_cast<const bf16x8*>(&Wl[(((size_t)nt*32 + kt)*64 + lane)*8]);
        acc[0][nt] = __builtin_amdgcn_mfma_f32_16x16x32_bf16(u0.v, Bf, acc[0][nt], 0, 0, 0);
        acc[1][nt] = __builtin_amdgcn_mfma_f32_16x16x32_bf16(u1.v, Bf, acc[1][nt], 0, 0, 0);
      }
    }
    #pragma unroll
    for (int m = 0; m < 2; ++m)
      #pragma unroll
      for (int n = 0; n < 3; ++n)
        #pragma unroll
        for (int e = 0; e < 4; ++e)
          red[wv][m*16 + r0 + e][n*16 + cc] = acc[m][n][e];
    __syncthreads();
    float hnew[2];
    #pragma unroll
    for (int u2 = 0; u2 < 2; ++u2){
      int jj = jp*2 + u2;
      float r_ = 0.f, z_ = 0.f, n_ = 0.f;
      #pragma unroll
      for (int w = 0; w < 4; ++w){
        r_ += red[w][b][jj]; z_ += red[w][b][16+jj]; n_ += red[w][b][32+jj];
      }
      const float* gr = gi + ((size_t)(c*BB) + b)*G6 + wg*16 + jj;
      float rr = sigm(gr[0]    + bhh[0][u2] + r_);
      float zz = sigm(gr[1024] + bhh[1][u2] + z_);
      float nn = tanhf(gr[2048] + rr*(bhh[2][u2] + n_));
      hnew[u2] = tanhf((1.f - zz)*nn + zz*hold[u2]);
      hold[u2] = hnew[u2];
    }
    {
      int kt = j0 >> 5, ln = (b & 15) + 16*((j0 >> 3) & 3), rg = j0 & 7, mt = b >> 4;
      unsigned pk = (unsigned)__builtin_bit_cast(unsigned short, (bf16_t)hnew[0])
                  | ((unsigned)__builtin_bit_cast(unsigned short, (bf16_t)hnew[1]) << 16);
      unsigned* dst = (unsigned*)(hdp + (size_t)((c+1)&1)*2*32*64*8 +
                                  (((size_t)(mt*32 + kt)*64 + ln)*8 + rg));
      ASTORE(dst, pk);
    }
    __syncthreads();
    if (tid == 0)
      ASTORE(dfh + wg*16, (unsigned)(c+1));
    if (wg < 16){
      {
        const unsigned int* fp = dfh + lane*16;
        unsigned tgt = (unsigned)(c+1);
        for(;;){
          unsigned v = ALOAD(fp);
          if (__ballot(v < tgt) == 0ull) break;
        }
      }
      f32x4 pacc[2] = {zero, zero};
      const bf16_t* hb2 = hdp + (size_t)((c+1)&1)*2*32*64*8;
      #pragma unroll
      for (int i = 0; i < 8; ++i){
        int kt = wv*8 + i;
        HU u0, u1;
        const unsigned long long* p0 = (const unsigned long long*)(hb2 + (((size_t)0*32 + kt)*64 + lane)*8);
        const unsigned long long* p1 = (const unsigned long long*)(hb2 + (((size_t)1*32 + kt)*64 + lane)*8);
        u0.u[0] = ALOAD(p0);     u0.u[1] = ALOAD(p0 + 1);
        u1.u[0] = ALOAD(p1);     u1.u[1] = ALOAD(p1 + 1);
        bf16x8 Bf = *reinterpret_cast<const bf16x8*>(Ppw + (((size_t)wg*32 + kt)*64 + lane)*8);
        pacc[0] = __builtin_amdgcn_mfma_f32_16x16x32_bf16(u0.v, Bf, pacc[0], 0, 0, 0);
        pacc[1] = __builtin_amdgcn_mfma_f32_16x16x32_bf16(u1.v, Bf, pacc[1], 0, 0, 0);
      }
      #pragma unroll
      for (int m = 0; m < 2; ++m)
        #pragma unroll
        for (int e = 0; e < 4; ++e)
          red[wv][m*16 + r0 + e][cc] = pacc[m][e];
      __syncthreads();
      {
        int colp = tid >> 5;
        float v0 = 0.f, v1 = 0.f;
        #pragma unroll
        for (int w = 0; w < 4; ++w){
          v0 += red[w][b][colp*2];
          v1 += red[w][b][colp*2+1];
        }
        int c0 = wg*16 + colp*2, c1 = c0 + 1;
        plred[colp][b][0] = v0*cls_w[c0]      + v1*cls_w[c1];
        plred[colp][b][1] = v0*cls_w[PP + c0] + v1*cls_w[PP + c1];
      }
      __syncthreads();
      if (tid < 32){
        float s0 = 0.f, s1 = 0.f;
        #pragma unroll
        for (int g = 0; g < 8; ++g){ s0 += plred[g][tid][0]; s1 += plred[g][tid][1]; }
        unsigned* dp = (unsigned*)(pl + (((size_t)c*16 + wg)*32 + tid)*2);
        ASTORE(dp,     __builtin_bit_cast(unsigned, s0));
        ASTORE(dp + 1, __builtin_bit_cast(unsigned, s1));
      }
      __syncthreads();
      if (tid == 0)
        ASTORE(dfpl + wg*16, (unsigned)(c+1));
    }
  }
  if (wg == 0){
    if (lane < 16){
      const unsigned int* fp = dfpl + lane*16;
      for(;;){
        unsigned v = ALOAD(fp);
        if (__ballot(v < 6u) == 0ull) break;
      }
    }
    __syncthreads();
    float* cr = (float*)red;
    cr[tid*2]   = proj_b[tid]*cls_w[tid];
    cr[tid*2+1] = proj_b[tid]*cls_w[PP + tid];
    __syncthreads();
    if (tid < 2){
      float s = 0.f;
      for (int i = 0; i < 256; ++i) s += cr[i*2 + tid];
      cv[tid] = s;
    }
    __syncthreads();
    if (tid < 32){
      for (int c = 0; c < 6; ++c){
        float a0 = cv[0] + cls_b[0], a1 = cv[1] + cls_b[1];
        for (int w = 0; w < 16; ++w){
          const unsigned* dp = (const unsigned*)(pl + (((size_t)c*16 + w)*32 + tid)*2);
          a0 += __builtin_bit_cast(float, ALOAD(dp));
          a1 += __builtin_bit_cast(float, ALOAD(dp + 1));
        }
        float mx = fmaxf(a0, a1);
        float ls = mx + logf(expf(a0 - mx) + expf(a1 - mx));
        out[((size_t)c*BB + tid)*2 + 0] = a0 - ls;
        out[((size_t)c*BB + tid)*2 + 1] = a1 - ls;
      }
    }
  }
}

// ================================= host ===================================================
extern "C" void kernel_launch(void* const* d_in, const int* in_sizes, int n_in,
                              void* d_out, int out_size, void* d_ws, size_t ws_size,
                              hipStream_t stream){
  const int*   seq          = (const int*)  d_in[0];
  const int*   seq_char     = (const int*)  d_in[1];
  const int*   classes      = (const int*)  d_in[2];
  const float* embed_w      = (const float*)d_in[3];
  const float* char_embed_w = (const float*)d_in[4];
  const float* class_embed_w= (const float*)d_in[5];
  const float* char_conv_w  = (const float*)d_in[6];
  const float* char_conv_b  = (const float*)d_in[7];
  const float* word_conv_w  = (const float*)d_in[8];
  const float* word_conv_b  = (const float*)d_in[9];
  const float* f_Wih = (const float*)d_in[10];
  const float* f_Whh = (const float*)d_in[11];
  const float* f_b   = (const float*)d_in[12];
  const float* b_Wih = (const float*)d_in[13];
  const float* b_Whh = (const float*)d_in[14];
  const float* b_b   = (const float*)d_in[15];
  const float* attend = (const float*)d_in[16];
  const float* d_Wih  = (const float*)d_in[17];
  const float* d_Whh  = (const float*)d_in[18];
  const float* d_bih  = (const float*)d_in[19];
  const float* d_bhh  = (const float*)d_in[20];
  const float* proj_w = (const float*)d_in[21];
  const float* proj_b = (const float*)d_in[22];
  const float* cls_w  = (const float*)d_in[23];
  const float* cls_b  = (const float*)d_in[24];
  float* out = (float*)d_out;

  char* wsb = (char*)d_ws;
  size_t off = 0;
  auto alloc = [&](size_t bytes) -> char* {
    char* p = wsb + off;
    off += (bytes + 255) & ~(size_t)255;
    return p;
  };
  // --- allocation layout BYTE-IDENTICAL to the proven 645us run (R4 submission) ---
  unsigned int* flags = (unsigned int*)alloc(12288);   // lf@0 | dfh@1024 | dfpl@2048 (dwords)
  unsigned int* lf   = flags;
  unsigned int* dfh  = flags + 1024;
  unsigned int* dfpl = flags + 2048;
  unsigned int* xcc_tab = (unsigned int*)alloc(1024);  // 256 dwords
  unsigned int* modep   = (unsigned int*)alloc(256);   // 64 dwords
  bf16_t* hp  = (bf16_t*)alloc((size_t)2*2*2*16*64*8 * 2);         // 128 KB (zeroed)
  const int ZERO_DWORDS = 3072 + 256 + 64 + 32768;                 // 36160
  bf16_t* hdp = (bf16_t*)alloc((size_t)2*2*32*64*8 * 2);           // 128 KB
  bf16_t* Wp  = (bf16_t*)alloc((size_t)2*32*NKT*4*64*8 * 2);
  bf16_t* Whp = (bf16_t*)alloc((size_t)64*3*32*64*8 * 2);
  bf16_t* Ppw = (bf16_t*)alloc((size_t)16*32*64*8 * 2);
  bf16_t* xp  = (bf16_t*)alloc((size_t)128*2*NKTX*64*8 * 2);
  float* pl       = (float*)alloc((size_t)6*16*32*2*4);
  float* x        = (float*)alloc((size_t)BB*SS*EC*4);
  float* mask     = (float*)alloc((size_t)BB*SS*4);
  float* cbar     = (float*)alloc((size_t)4096*512*4);
  float* xbar     = (float*)alloc((size_t)BB*EC*64*4);
  float* conv_seq = (float*)alloc((size_t)BB*256*4);
  float* seq_repr = (float*)alloc((size_t)BB*SS*H2*4);
  float* ta       = (float*)alloc((size_t)6*H2*4);
  float* ctx      = (float*)alloc((size_t)6*BB*H2*4);
  float* inp      = (float*)alloc((size_t)192*1280*4);   // kept (unused) for layout parity
  float* gi       = (float*)alloc((size_t)192*G6*4);
  float* part_char= (float*)alloc((size_t)2*4096*64*4);  // kept (unused) for layout parity
  float* part_word= (float*)alloc((size_t)32*BB*256*4);
  float* part_gi  = (float*)alloc((size_t)4*192*G6*4);
  (void)ws_size; (void)in_sizes; (void)n_in; (void)out_size;
  (void)inp; (void)part_char;

  k_zero<<<(ZERO_DWORDS + 255)/256, 256, 0, stream>>>((unsigned int*)d_ws, ZERO_DWORDS);

  k_packw<<<2*32*NKT, 64, 0, stream>>>(f_Wih, f_Whh, b_Wih, b_Whh, Wp);
  k_packdw<<<64*3*32, 64, 0, stream>>>(d_Whh, Whp);
  k_packpw<<<16*32, 64, 0, stream>>>(proj_w, Ppw);
  k_embed_cbar<<<BB*SS, 256, 0, stream>>>(seq, embed_w, seq_char, char_embed_w, x, mask, cbar);
  k_cgemm<<<128, 256, 0, stream>>>(cbar, char_conv_w, char_conv_b, x);
  k_xbar<<<160, 64, 0, stream>>>(x, xbar);
  k_gemm<32,64,2,4><<<dim3(1,4,32), 256, 0, stream>>>(xbar, word_conv_w, part_word, 32, 256, 20480, 640);
  k_fin<<<dim3(4,32), 64, 0, stream>>>(part_word, word_conv_b, conv_seq, 32, 256, 32, 256, 1);
  k_packx<<<128*2*NKTX, 64, 0, stream>>>(x, xp);
  k_lstm<<<256, 256, 0, stream>>>(Wp, xp, hp, f_b, b_b, seq_repr, lf, xcc_tab, modep);
  k_ta<<<6, 256, 0, stream>>>(classes, class_embed_w, attend, ta);
  k_ctx<<<dim3(6,32), 256, 0, stream>>>(ta, seq_repr, mask, ctx);
  k_gemmgi<<<dim3(3,48,4), 256, 0, stream>>>(conv_seq, ctx, d_Wih, part_gi);
  k_fin<<<dim3(48,192), 64, 0, stream>>>(part_gi, d_bih, gi, 192, G6, 4, G6, 0);
  k_hprep<<<64, 64, 0, stream>>>(seq_repr, hdp);
  k_dec<<<64, 256, 0, stream>>>(Whp, Ppw, gi, d_bhh, seq_repr, proj_b, cls_w, cls_b,
                                hdp, pl, dfh, dfpl, out);
}

// Round 10
// 575.982 us; speedup vs baseline: 1.7489x; 1.1228x over previous
//
#include <hip/hip_runtime.h>

typedef __bf16 bf16_t;
typedef __bf16 bf16x8 __attribute__((ext_vector_type(8)));
typedef float f32x4 __attribute__((ext_vector_type(4)));
typedef unsigned u32x4 __attribute__((ext_vector_type(4)));
typedef unsigned long long u64;

static constexpr int BB = 32, SS = 128, WW = 16, EE = 256, CDm = 64, HH = 512, PP = 256;
static constexpr int EC = 320;    // E + CD
static constexpr int H2 = 1024;   // 2H
static constexpr int G6 = 3072;   // 6H
static constexpr int NKT = 28;    // 16 h-ktiles + 12 x-ktiles (x padded 320->384)
static constexpr int NKTX = 12;

__device__ __forceinline__ float sigm(float x){ return 1.f/(1.f + expf(-x)); }
// fast, overflow-safe gate activations (v_exp based)
__device__ __forceinline__ float fsigm(float x){ return 1.f/(1.f + __expf(-x)); }
__device__ __forceinline__ float ftanh(float x){ return 1.f - 2.f/(1.f + __expf(2.f*x)); }

#define ALOAD(p)    __hip_atomic_load((p),  __ATOMIC_RELAXED, __HIP_MEMORY_SCOPE_AGENT)
#define ASTORE(p,v) __hip_atomic_store((p),(v),__ATOMIC_RELAXED, __HIP_MEMORY_SCOPE_AGENT)

// ---- dual-mode memory ops: LLC=true -> sc0 sc1 (device coherence point);
// ----                       LLC=false -> sc0 only (XCD-local L2, same-XCD coherent)
template<bool LLC>
__device__ __forceinline__ unsigned ld_flag(const unsigned* p){
  unsigned r;
  if constexpr (LLC)
    asm volatile("global_load_dword %0, %1, off sc0 sc1\n\ts_waitcnt vmcnt(0)"
                 : "=&v"(r) : "v"(p) : "memory");
  else
    asm volatile("global_load_dword %0, %1, off sc0\n\ts_waitcnt vmcnt(0)"
                 : "=&v"(r) : "v"(p) : "memory");
  return r;
}
template<bool LLC>
__device__ __forceinline__ void ld16(u32x4& d, const void* p){
  if constexpr (LLC)
    asm volatile("global_load_dwordx4 %0, %1, off sc0 sc1" : "=&v"(d) : "v"(p) : "memory");
  else
    asm volatile("global_load_dwordx4 %0, %1, off sc0"     : "=&v"(d) : "v"(p) : "memory");
}
template<bool LLC>
__device__ __forceinline__ void st32(unsigned* p, unsigned v){
  if constexpr (LLC)
    asm volatile("global_store_dword %0, %1, off sc0 sc1" :: "v"(p), "v"(v) : "memory");
  else
    asm volatile("global_store_dword %0, %1, off sc0"     :: "v"(p), "v"(v) : "memory");
}
__device__ __forceinline__ void vm_drain(){
  asm volatile("s_waitcnt vmcnt(0)" ::: "memory");
  __builtin_amdgcn_sched_barrier(0);
}

// ---------------- embedding + char means (fused; proven R9) -------------------------------
__global__ void k_embed_cbar(const int* __restrict__ seq, const float* __restrict__ embed_w,
                             const int* __restrict__ seq_char, const float* __restrict__ cemb,
                             float* __restrict__ x, float* __restrict__ mask,
                             float* __restrict__ cbar){
  int bs = blockIdx.x; int tid = threadIdx.x;
  int wid = seq[bs];
  x[(size_t)bs*EC + tid] = tanhf(embed_w[(size_t)wid*EE + tid]);
  if (tid == 0) mask[bs] = (wid > 0) ? 1.f : 0.f;
  if (tid < 64){
    int c = tid;
    float ce[WW];
    #pragma unroll
    for (int p = 0; p < WW; ++p){
      int id = seq_char[bs*WW + p];
      ce[p] = cemb[(size_t)id*CDm + c];
    }
    #pragma unroll
    for (int k = 0; k < 8; ++k){
      float s = 0.f;
      #pragma unroll
      for (int p = 0; p < 9; ++p) s += ce[k+p];
      cbar[(size_t)bs*512 + c*8 + k] = s * (1.f/9.f);
    }
  }
}

// ---------------- x sliding means ---------------------------------------------------------
__global__ __launch_bounds__(64) void k_xbar(const float* __restrict__ x, float* __restrict__ xbar){
  __shared__ float xl[64][129];
  int gid = blockIdx.x*64 + threadIdx.x;  // 0..10239
  int b = gid / EC, c = gid % EC;
  int tl = threadIdx.x;
  for (int t = 0; t < SS; ++t) xl[tl][t] = x[((size_t)b*SS + t)*EC + c];
  float s = 0.f;
  for (int t = 0; t < 65; ++t) s += xl[tl][t];
  const float inv = 1.f/65.f;
  float* o = &xbar[(size_t)(b*EC + c)*64];
  o[0] = s*inv;
  for (int k = 1; k < 64; ++k){ s += xl[tl][k+64] - xl[tl][k-1]; o[k] = s*inv; }
}

// ---------------- generic fp32 tiled GEMM -------------------------------------------------
template<int BM,int BN,int TM,int TN>
__global__ __launch_bounds__(256) void k_gemm(const float* __restrict__ A,
    const float* __restrict__ Wm, float* __restrict__ part,
    int M, int N, int K, int kslice){
  __shared__ float As[32][BM+4];
  __shared__ float Ws[32][BN+4];
  const int tid = threadIdx.x;
  const int tx = tid & 15, ty = tid >> 4;
  const int m0 = blockIdx.x*BM, n0 = blockIdx.y*BN, ks = blockIdx.z;
  const int kb = ks*kslice;
  float acc[TM][TN];
  #pragma unroll
  for (int i = 0; i < TM; ++i)
    #pragma unroll
    for (int j = 0; j < TN; ++j) acc[i][j] = 0.f;
  for (int kt = 0; kt < kslice; kt += 32){
    constexpr int AIT = (BM*8)/256;
    #pragma unroll
    for (int it = 0; it < AIT; ++it){
      int ch = tid + it*256;
      int r = ch >> 3, kc = (ch & 7)*4;
      float4 v = *(const float4*)(A + (size_t)(m0+r)*K + kb + kt + kc);
      As[kc+0][r]=v.x; As[kc+1][r]=v.y; As[kc+2][r]=v.z; As[kc+3][r]=v.w;
    }
    constexpr int WIT = (BN*8)/256;
    #pragma unroll
    for (int it = 0; it < WIT; ++it){
      int ch = tid + it*256;
      int r = ch >> 3, kc = (ch & 7)*4;
      float4 v = *(const float4*)(Wm + (size_t)(n0+r)*K + kb + kt + kc);
      Ws[kc+0][r]=v.x; Ws[kc+1][r]=v.y; Ws[kc+2][r]=v.z; Ws[kc+3][r]=v.w;
    }
    __syncthreads();
    #pragma unroll
    for (int kk = 0; kk < 32; ++kk){
      float a[TM], wv[TN];
      #pragma unroll
      for (int i = 0; i < TM; ++i) a[i] = As[kk][ty*TM+i];
      #pragma unroll
      for (int j = 0; j < TN; ++j) wv[j] = Ws[kk][tx*TN+j];
      #pragma unroll
      for (int i = 0; i < TM; ++i)
        #pragma unroll
        for (int j = 0; j < TN; ++j) acc[i][j] = fmaf(a[i], wv[j], acc[i][j]);
    }
    __syncthreads();
  }
  #pragma unroll
  for (int i = 0; i < TM; ++i){
    int row = m0 + ty*TM + i;
    #pragma unroll
    for (int j = 0; j < TN; ++j){
      int col = n0 + tx*TN + j;
      part[((size_t)ks*M + row)*N + col] = acc[i][j];
    }
  }
}

// ---------------- char conv GEMM, fused bias+tanh -> x[:,256:320] (proven R9) -------------
__global__ __launch_bounds__(256) void k_cgemm(const float* __restrict__ A,
    const float* __restrict__ Wm, const float* __restrict__ bias, float* __restrict__ x){
  __shared__ float As[32][36];
  __shared__ float Ws[32][68];
  const int tid = threadIdx.x;
  const int tx = tid & 15, ty = tid >> 4;
  const int m0 = blockIdx.x*32;
  float acc[2][4];
  #pragma unroll
  for (int i = 0; i < 2; ++i)
    #pragma unroll
    for (int j = 0; j < 4; ++j) acc[i][j] = 0.f;
  for (int kt = 0; kt < 512; kt += 32){
    {
      int r = tid >> 3, kc = (tid & 7)*4;
      float4 v = *(const float4*)(A + (size_t)(m0+r)*512 + kt + kc);
      As[kc+0][r]=v.x; As[kc+1][r]=v.y; As[kc+2][r]=v.z; As[kc+3][r]=v.w;
    }
    #pragma unroll
    for (int it = 0; it < 2; ++it){
      int ch = tid + it*256;
      int r = ch >> 3, kc = (ch & 7)*4;
      float4 v = *(const float4*)(Wm + (size_t)r*512 + kt + kc);
      Ws[kc+0][r]=v.x; Ws[kc+1][r]=v.y; Ws[kc+2][r]=v.z; Ws[kc+3][r]=v.w;
    }
    __syncthreads();
    #pragma unroll
    for (int kk = 0; kk < 32; ++kk){
      float a[2], wv[4];
      a[0] = As[kk][ty*2]; a[1] = As[kk][ty*2+1];
      #pragma unroll
      for (int j = 0; j < 4; ++j) wv[j] = Ws[kk][tx*4+j];
      #pragma unroll
      for (int i = 0; i < 2; ++i)
        #pragma unroll
        for (int j = 0; j < 4; ++j) acc[i][j] = fmaf(a[i], wv[j], acc[i][j]);
    }
    __syncthreads();
  }
  #pragma unroll
  for (int i = 0; i < 2; ++i){
    int row = m0 + ty*2 + i;
    #pragma unroll
    for (int j = 0; j < 4; ++j){
      int col = tx*4 + j;
      x[(size_t)row*EC + 256 + col] = tanhf(acc[i][j] + bias[col]);
    }
  }
}

// ---------------- finalize partials -------------------------------------------------------
__global__ __launch_bounds__(64) void k_fin(const float* __restrict__ part,
    const float* __restrict__ bias, float* __restrict__ out,
    int M, int N, int KS, int ldc, int act){
  int col = blockIdx.x*64 + threadIdx.x;
  int row = blockIdx.y;
  float v = bias ? bias[col] : 0.f;
  for (int ks = 0; ks < KS; ++ks) v += part[((size_t)ks*M + row)*N + col];
  if (act) v = tanhf(v);
  out[(size_t)row*ldc + col] = v;
}

// ---------------- merged prep: zero + packw + packdw + packpw (one launch) ----------------
// roles by blockIdx: [0,1792) packw | [1792,7936) packdw | [7936,8448) packpw | rest zero
__global__ __launch_bounds__(64) void k_prep(
    const float* __restrict__ fWih, const float* __restrict__ fWhh,
    const float* __restrict__ bWih, const float* __restrict__ bWhh, bf16_t* __restrict__ Wp,
    const float* __restrict__ dWhh, bf16_t* __restrict__ Whp,
    const float* __restrict__ projw, bf16_t* __restrict__ Ppw,
    unsigned int* __restrict__ zbase, int nzero){
  int blk = blockIdx.x;
  int l = threadIdx.x;
  if (blk < 1792){
    int id = blk;
    int kt = id % NKT; id /= NKT;
    int slice = id % 32; int dir = id / 32;
    const float* Whh = dir ? bWhh : fWhh;
    const float* Wih = dir ? bWih : fWih;
    int krow = (l >> 4)*8;
    for (int nt = 0; nt < 4; ++nt){
      int row = nt*512 + slice*16 + (l & 15);
      bf16_t* dst = &Wp[((((size_t)(dir*32+slice)*NKT + kt)*4 + nt)*64 + l)*8];
      if (kt < 16){
        const float* src = &Whh[(size_t)row*512 + kt*32 + krow];
        #pragma unroll
        for (int r = 0; r < 8; ++r) dst[r] = (bf16_t)src[r];
      } else {
        int kx = (kt-16)*32 + krow;
        if (kx + 8 <= 320){
          const float* src = &Wih[(size_t)row*320 + kx];
          #pragma unroll
          for (int r = 0; r < 8; ++r) dst[r] = (bf16_t)src[r];
        } else {
          #pragma unroll
          for (int r = 0; r < 8; ++r) dst[r] = (bf16_t)0.f;
        }
      }
    }
  } else if (blk < 7936){
    int id = blk - 1792;
    int kt = id % 32; id /= 32;
    int nt = id % 3;  int wg = id / 3;
    int col = nt*1024 + wg*16 + (l & 15);
    int k0 = kt*32 + (l >> 4)*8;
    bf16_t* dst = Whp + (((size_t)(wg*3 + nt)*32 + kt)*64 + l)*8;
    const float* src = dWhh + (size_t)col*1024 + k0;
    #pragma unroll
    for (int r = 0; r < 8; ++r) dst[r] = (bf16_t)src[r];
  } else if (blk < 8448){
    int id = blk - 7936;
    int kt = id & 31, wg = id >> 5;
    int col = wg*16 + (l & 15);
    int k0 = kt*32 + (l >> 4)*8;
    bf16_t* dst = Ppw + (((size_t)wg*32 + kt)*64 + l)*8;
    const float* src = projw + (size_t)col*1024 + k0;
    #pragma unroll
    for (int r = 0; r < 8; ++r) dst[r] = (bf16_t)src[r];
  } else {
    int i = (blk - 8448)*64 + l;
    if (i < nzero) ASTORE(zbase + i, 0u);
  }
}

// ---------------- pack x into A-fragment order --------------------------------------------
__global__ __launch_bounds__(64) void k_packx(const float* __restrict__ x, bf16_t* __restrict__ xp){
  int id = blockIdx.x;
  int ktx = id % NKTX; id /= NKTX;
  int mt = id & 1; int t = id >> 1;        // 0..127
  int l = threadIdx.x;
  int b = (l & 15) + 16*mt;
  int c = ktx*32 + (l >> 4)*8;
  bf16_t* dst = &xp[(((size_t)t*2 + mt)*NKTX + ktx)*64*8 + (size_t)l*8];
  if (c + 8 <= EC){
    const float* src = &x[((size_t)b*SS + t)*EC + c];
    #pragma unroll
    for (int r = 0; r < 8; ++r) dst[r] = (bf16_t)src[r];
  } else {
    #pragma unroll
    for (int r = 0; r < 8; ++r) dst[r] = (bf16_t)0.f;
  }
}

// ---------------- BiLSTM step-loop body, dual-mode (R9 skeleton + micro-trims) ------------
template<bool LLC>
__device__ void lstm_body(const bf16_t* __restrict__ Wp, const bf16_t* __restrict__ xp,
    bf16_t* __restrict__ hp, const float* __restrict__ fb, const float* __restrict__ bb,
    float* __restrict__ seq_repr, unsigned* __restrict__ lf, bf16_t* __restrict__ hdp,
    int dir, int slice, int tid, bf16_t* Wl, float (*red)[32][65],
    float* bias_l, float (*c_l)[32]){
  const int wv = tid >> 6, lane = tid & 63;
  {
    const uint4* src = (const uint4*)(Wp + ((size_t)(dir*32 + slice))*NKT*4*64*8);
    uint4* dst = (uint4*)Wl;
    for (int i = tid; i < NKT*4*64*8/8; i += 256) dst[i] = src[i];
  }
  if (tid < 64){
    const float* bv = dir ? bb : fb;
    bias_l[tid] = bv[(tid >> 4)*512 + slice*16 + (tid & 15)];
  }
  ((float*)c_l)[tid]       = 0.f;
  ((float*)c_l)[tid + 256] = 0.f;
  __syncthreads();

  for (int t = 0; t < SS; ++t){
    const int ph = t & 1;
    const int s = dir ? ((SS - t) & 127) : t;
    f32x4 acc[2][4];
    f32x4 zero = {0.f,0.f,0.f,0.f};
    #pragma unroll
    for (int m = 0; m < 2; ++m)
      #pragma unroll
      for (int n = 0; n < 4; ++n) acc[m][n] = zero;

    // ---- x loads + x MFMAs (overlap the poll below) ------------------------------------
    const bf16_t* xb = xp + (size_t)s*2*NKTX*64*8;
    bf16x8 ax[3][2];
    #pragma unroll
    for (int i = 0; i < 3; ++i){
      int ktx = wv*3 + i;
      #pragma unroll
      for (int m = 0; m < 2; ++m)
        ax[i][m] = *reinterpret_cast<const bf16x8*>(xb + (((size_t)m*NKTX + ktx)*64 + lane)*8);
    }
    #pragma unroll
    for (int i = 0; i < 3; ++i){
      int kt = 16 + wv*3 + i;
      #pragma unroll
      for (int nt = 0; nt < 4; ++nt){
        bf16x8 Bf = *reinterpret_cast<const bf16x8*>(&Wl[(((size_t)kt*4 + nt)*64 + lane)*8]);
        acc[0][nt] = __builtin_amdgcn_mfma_f32_16x16x32_bf16(ax[i][0], Bf, acc[0][nt], 0, 0, 0);
        acc[1][nt] = __builtin_amdgcn_mfma_f32_16x16x32_bf16(ax[i][1], Bf, acc[1][nt], 0, 0, 0);
      }
    }
    // ---- per-wave poll: only this wave's 8 producers (WG union covers all 32) ----------
    if (t > 0 && lane < 8){
      int prod = dir*32 + (wv + 4*(lane >> 1))*2 + (lane & 1);
      const unsigned* fp = lf + prod*16;
      unsigned tgt = (unsigned)t;
      for(;;){
        unsigned v = ld_flag<LLC>(fp);
        if (__ballot(v < tgt) == 0ull) break;
      }
    }
    // ---- h fragment loads + MFMAs ------------------------------------------------------
    const bf16_t* hb_ = hp + ((size_t)(ph*2 + dir))*2*16*64*8;
    u32x4 hr[4][2];
    #pragma unroll
    for (int i = 0; i < 4; ++i){
      int kt = wv + 4*i;
      #pragma unroll
      for (int m = 0; m < 2; ++m)
        ld16<LLC>(hr[i][m], hb_ + (((size_t)m*16 + kt)*64 + lane)*8);
    }
    vm_drain();
    #pragma unroll
    for (int i = 0; i < 4; ++i){
      int kt = wv + 4*i;
      bf16x8 a0 = __builtin_bit_cast(bf16x8, hr[i][0]);
      bf16x8 a1 = __builtin_bit_cast(bf16x8, hr[i][1]);
      #pragma unroll
      for (int nt = 0; nt < 4; ++nt){
        bf16x8 Bf = *reinterpret_cast<const bf16x8*>(&Wl[(((size_t)kt*4 + nt)*64 + lane)*8]);
        acc[0][nt] = __builtin_amdgcn_mfma_f32_16x16x32_bf16(a0, Bf, acc[0][nt], 0, 0, 0);
        acc[1][nt] = __builtin_amdgcn_mfma_f32_16x16x32_bf16(a1, Bf, acc[1][nt], 0, 0, 0);
      }
    }
    // ---- cross-wave K-reduction --------------------------------------------------------
    {
      int r0 = (lane >> 4)*4, cc = lane & 15;
      #pragma unroll
      for (int m = 0; m < 2; ++m)
        #pragma unroll
        for (int n = 0; n < 4; ++n)
          #pragma unroll
          for (int e = 0; e < 4; ++e)
            red[wv][m*16 + r0 + e][n*16 + cc] = acc[m][n][e];
    }
    __syncthreads();
    // ---- gates + state update (fast transcendentals) -----------------------------------
    const int b = tid & 31, jjp = tid >> 5;
    float hv[2];
    #pragma unroll
    for (int u2 = 0; u2 < 2; ++u2){
      int jj = jjp*2 + u2;
      float gi_ = bias_l[jj],     gf_ = bias_l[16+jj];
      float gg_ = bias_l[32+jj],  go_ = bias_l[48+jj];
      #pragma unroll
      for (int w2 = 0; w2 < 4; ++w2){
        gi_ += red[w2][b][jj];      gf_ += red[w2][b][16+jj];
        gg_ += red[w2][b][32+jj];   go_ += red[w2][b][48+jj];
      }
      float ii = fsigm(gi_), ff = fsigm(gf_), g2 = ftanh(gg_), oo = fsigm(go_);
      float c = ff*c_l[jj][b] + ii*g2;
      c_l[jj][b] = c;
      hv[u2] = oo*ftanh(c);
    }
    const int j0 = slice*16 + jjp*2;
    unsigned pk = (unsigned)__builtin_bit_cast(unsigned short, (bf16_t)hv[0])
                | ((unsigned)__builtin_bit_cast(unsigned short, (bf16_t)hv[1]) << 16);
    {
      int mt = b >> 4, kth = j0 >> 5, ln = (b & 15) + 16*((j0 >> 3) & 3), rg = j0 & 7;
      unsigned* dst = (unsigned*)(hp +
          ((((size_t)((ph^1)*2 + dir)*2 + mt)*16 + kth)*64 + ln)*8 + rg);
      st32<LLC>(dst, pk);
      // fold decoder-h0 pack: dir0 last step / dir1 first step (global j = dir*512 + j0)
      if ((dir == 0 && t == 127) || (dir == 1 && t == 0)){
        int ktd = dir*16 + kth;
        ASTORE((unsigned*)(hdp + (((size_t)(mt*32 + ktd)*64 + ln)*8 + rg)), pk);
      }
    }
    // drain own h store, join, then publish flag
    asm volatile("s_waitcnt vmcnt(0)" ::: "memory");
    __syncthreads();
    if (tid == 0)
      st32<LLC>(lf + (dir*32 + slice)*16, (unsigned)(t+1));
    // ---- seq_repr store deferred past the flag (off the critical path) -----------------
    {
      int s_out = dir ? (127 - t) : t;
      float2 st; st.x = hv[0]; st.y = hv[1];
      *(float2*)&seq_repr[((size_t)b*SS + s_out)*H2 + dir*HH + j0] = st;
    }
  }
}

// ---------------- persistent BiLSTM with runtime XCD-placement detection ------------------
// Non-worker blocks: 6 of them compute k_ta's class-attention vectors (free overlap).
__global__ __launch_bounds__(256, 1) void k_lstm(const bf16_t* __restrict__ Wp,
    const bf16_t* __restrict__ xp, bf16_t* __restrict__ hp,
    const float* __restrict__ fb, const float* __restrict__ bb,
    float* __restrict__ seq_repr, unsigned* __restrict__ lf,
    unsigned* __restrict__ xcc_tab, unsigned* __restrict__ modep,
    bf16_t* __restrict__ hdp,
    const int* __restrict__ classes, const float* __restrict__ cls_emb,
    const float* __restrict__ attend, float* __restrict__ ta){
  const int blk = blockIdx.x;
  const int tid = threadIdx.x;
  __shared__ __align__(16) bf16_t Wl[NKT*4*64*8];   // 114688 B
  __shared__ float red[4][32][65];
  __shared__ float bias_l[64];
  __shared__ float c_l[16][32];
  __shared__ unsigned mode_s;

  unsigned xcc;
  asm volatile("s_getreg_b32 %0, hwreg(HW_REG_XCC_ID)" : "=s"(xcc));
  if (tid == 0) ASTORE(xcc_tab + blk, xcc + 1u);
  if (blk == 0){
    unsigned* tabl = (unsigned*)red;
    unsigned v = 0; int spins = 0;
    for (;;){
      v = ALOAD(xcc_tab + tid);
      if (v != 0u || spins >= 200000) break;
      ++spins; __builtin_amdgcn_s_sleep(2);
    }
    tabl[tid] = v;
    __syncthreads();
    if (tid == 0){
      unsigned mode = 1;
      unsigned c0 = tabl[0], c1 = tabl[1];
      if (c0 == 0u || c1 == 0u) mode = 2;
      for (int k = 0; k < 32; ++k)
        if (tabl[8*k] != c0 || tabl[8*k + 1] != c1) mode = 2;
      ASTORE(modep, mode);
      mode_s = mode;
    }
    __syncthreads();
  } else {
    if (tid == 0){
      unsigned m;
      while ((m = ALOAD(modep)) == 0u) __builtin_amdgcn_s_sleep(2);
      mode_s = m;
    }
    __syncthreads();
  }
  const unsigned mode = mode_s;
  int dir, slice; bool worker;
  if (mode == 1){ worker = (blk & 7) < 2; dir = blk & 7; slice = blk >> 3; }
  else          { worker = blk < 64;      dir = blk >> 5; slice = blk & 31; }
  if (!worker){
    // ta on 6 idle blocks (uniform per-block branch)
    bool ta_blk; int c;
    if (mode == 1){ ta_blk = ((blk & 7) == 2) && ((blk >> 3) < 6); c = blk >> 3; }
    else          { ta_blk = (blk >= 64 && blk < 70);              c = blk - 64; }
    if (ta_blk){
      float* t2 = (float*)red;
      int ci = classes[c];
      t2[tid] = tanhf(tanhf(cls_emb[(size_t)ci*EE + tid]));
      __syncthreads();
      for (int r = 0; r < 4; ++r){
        int h = r*256 + tid;
        float a2 = 0.f;
        for (int e = 0; e < EE; ++e) a2 = fmaf(t2[e], attend[(size_t)e*H2 + h], a2);
        ta[c*H2 + h] = tanhf(a2);
      }
    }
    return;
  }
  if (mode == 1)
    lstm_body<false>(Wp, xp, hp, fb, bb, seq_repr, lf, hdp, dir, slice, tid, Wl, red, bias_l, c_l);
  else
    lstm_body<true >(Wp, xp, hp, fb, bb, seq_repr, lf, hdp, dir, slice, tid, Wl, red, bias_l, c_l);
}

// ---------------- attention context -------------------------------------------------------
__global__ __launch_bounds__(256) void k_ctx(const float* __restrict__ ta,
    const float* __restrict__ seq_repr, const float* __restrict__ mask, float* __restrict__ ctx){
  int c = blockIdx.x, b = blockIdx.y;
  __shared__ float ta_l[H2];
  __shared__ float ps[128][2];
  __shared__ float sc[128];
  int tid = threadIdx.x;
  for (int i = tid; i < H2; i += 256) ta_l[i] = ta[c*H2 + i];
  __syncthreads();
  {
    int tt = tid >> 1, half = tid & 1;
    const float* row = &seq_repr[((size_t)b*SS + tt)*H2 + half*512];
    const float* tl = &ta_l[half*512];
    float p = 0.f;
    for (int i = 0; i < 512; i += 4){
      float4 v = *(const float4*)&row[i];
      p = fmaf(tl[i], v.x, p);   p = fmaf(tl[i+1], v.y, p);
      p = fmaf(tl[i+2], v.z, p); p = fmaf(tl[i+3], v.w, p);
    }
    ps[tt][half] = p;
  }
  __syncthreads();
  if (tid < 128){
    float s = (ps[tid][0] + ps[tid][1]) * 128.f * mask[b*SS + tid];
    sc[tid] = tanhf(s);
  }
  __syncthreads();
  {
    int h = tid*4;
    float4 a = {0.f,0.f,0.f,0.f};
    for (int t = 0; t < SS; ++t){
      float s = sc[t];
      float4 v = *(const float4*)&seq_repr[((size_t)b*SS + t)*H2 + h];
      a.x = fmaf(s, v.x, a.x); a.y = fmaf(s, v.y, a.y);
      a.z = fmaf(s, v.z, a.z); a.w = fmaf(s, v.w, a.w);
    }
    *(float4*)&ctx[((size_t)c*BB + b)*H2 + h] = a;
  }
}

// ---------------- gi GEMM: A gathered from (conv_seq | ctx) (proven R9) -------------------
__global__ __launch_bounds__(256) void k_gemmgi(const float* __restrict__ conv_seq,
    const float* __restrict__ ctx, const float* __restrict__ Wm, float* __restrict__ part){
  __shared__ float As[32][68];
  __shared__ float Ws[32][68];
  const int tid = threadIdx.x;
  const int tx = tid & 15, ty = tid >> 4;
  const int m0 = blockIdx.x*64, n0 = blockIdx.y*64, ks = blockIdx.z;
  const int kb = ks*320;
  float acc[4][4];
  #pragma unroll
  for (int i = 0; i < 4; ++i)
    #pragma unroll
    for (int j = 0; j < 4; ++j) acc[i][j] = 0.f;
  for (int kt = 0; kt < 320; kt += 32){
    #pragma unroll
    for (int it = 0; it < 2; ++it){
      int ch = tid + it*256;
      int r = ch >> 3, kc = (ch & 7)*4;
      int row = m0 + r;
      int cc2 = row >> 5, bb2 = row & 31;
      int k4 = kb + kt + kc;
      const float* ap = (k4 < 256) ? (conv_seq + bb2*256 + k4)
                                   : (ctx + ((size_t)(cc2*BB) + bb2)*H2 + (k4 - 256));
      float4 v = *(const float4*)ap;
      As[kc+0][r]=v.x; As[kc+1][r]=v.y; As[kc+2][r]=v.z; As[kc+3][r]=v.w;
    }
    #pragma unroll
    for (int it = 0; it < 2; ++it){
      int ch = tid + it*256;
      int r = ch >> 3, kc = (ch & 7)*4;
      float4 v = *(const float4*)(Wm + (size_t)(n0+r)*1280 + kb + kt + kc);
      Ws[kc+0][r]=v.x; Ws[kc+1][r]=v.y; Ws[kc+2][r]=v.z; Ws[kc+3][r]=v.w;
    }
    __syncthreads();
    #pragma unroll
    for (int kk = 0; kk < 32; ++kk){
      float a[4], wv[4];
      #pragma unroll
      for (int i = 0; i < 4; ++i) a[i] = As[kk][ty*4+i];
      #pragma unroll
      for (int j = 0; j < 4; ++j) wv[j] = Ws[kk][tx*4+j];
      #pragma unroll
      for (int i = 0; i < 4; ++i)
        #pragma unroll
        for (int j = 0; j < 4; ++j) acc[i][j] = fmaf(a[i], wv[j], acc[i][j]);
    }
    __syncthreads();
  }
  #pragma unroll
  for (int i = 0; i < 4; ++i){
    int row = m0 + ty*4 + i;
    #pragma unroll
    for (int j = 0; j < 4; ++j){
      int col = n0 + tx*4 + j;
      part[((size_t)ks*192 + row)*G6 + col] = acc[i][j];
    }
  }
}

// ---------------- fused persistent GRU decoder: 64 WGs ------------------------------------
__global__ __launch_bounds__(256, 1) void k_dec(
    const bf16_t* __restrict__ Whp, const bf16_t* __restrict__ Ppw,
    const float* __restrict__ gi, const float* __restrict__ d_bhh,
    const float* __restrict__ seq_repr,
    const float* __restrict__ proj_b, const float* __restrict__ cls_w,
    const float* __restrict__ cls_b, bf16_t* __restrict__ hdp,
    float* __restrict__ pl, unsigned int* __restrict__ dfh,
    unsigned int* __restrict__ dfpl, float* __restrict__ out){
  const int wg = blockIdx.x;
  const int tid = threadIdx.x;
  const int wv = tid >> 6, lane = tid & 63;
  __shared__ __align__(16) bf16_t Wl[3*32*64*8];    // 98304 B
  __shared__ float red[4][32][49];                  // 25088 B
  __shared__ float plred[8][32][2];                 // 2048 B
  __shared__ float cv[2];
  {
    const uint4* src = (const uint4*)(Whp + (size_t)wg*3*32*64*8);
    uint4* dst = (uint4*)Wl;
    for (int i = tid; i < 3*32*64*8/8; i += 256) dst[i] = src[i];
  }
  const int b = tid & 31, jp = tid >> 5;
  const int j0 = wg*16 + jp*2;
  float hold[2];
  hold[0] = seq_repr[((size_t)b*SS + 127)*H2 + j0];
  hold[1] = seq_repr[((size_t)b*SS + 127)*H2 + j0 + 1];
  float bhh[3][2];
  #pragma unroll
  for (int g = 0; g < 3; ++g){
    bhh[g][0] = d_bhh[g*1024 + j0];
    bhh[g][1] = d_bhh[g*1024 + j0 + 1];
  }
  __syncthreads();
  union HU { unsigned long long u[2]; bf16x8 v; };
  const int r0 = (lane >> 4)*4, cc = lane & 15;

  for (int c = 0; c < 6; ++c){
    if (c > 0){
      const unsigned int* fp = dfh + lane*16;
      unsigned tgt = (unsigned)c;
      for(;;){
        unsigned v = ALOAD(fp);
        if (__ballot(v < tgt) == 0ull) break;
      }
    }
    f32x4 acc[2][3];
    f32x4 zero = {0.f,0.f,0.f,0.f};
    #pragma unroll
    for (int m = 0; m < 2; ++m)
      #pragma unroll
      for (int n = 0; n < 3; ++n) acc[m][n] = zero;
    const bf16_t* hb = hdp + (size_t)(c & 1)*2*32*64*8;
    #pragma unroll
    for (int i = 0; i < 8; ++i){
      int kt = wv*8 + i;
      HU u0, u1;
      const unsigned long long* p0 = (const unsigned long long*)(hb + (((size_t)0*32 + kt)*64 + lane)*8);
      const unsigned long long* p1 = (const unsigned long long*)(hb + (((size_t)1*32 + kt)*64 + lane)*8);
      u0.u[0] = ALOAD(p0);     u0.u[1] = ALOAD(p0 + 1);
      u1.u[0] = ALOAD(p1);     u1.u[1] = ALOAD(p1 + 1);
      #pragma unroll
      for (int nt = 0; nt < 3; ++nt){
        bf16x8 Bf = *reinterpret_cast<const bf16x8*>(&Wl[(((size_t)nt*32 + kt)*64 + lane)*8]);
        acc[0][nt] = __builtin_amdgcn_mfma_f32_16x16x32_bf16(u0.v, Bf, acc[0][nt], 0, 0, 0);
        acc[1][nt] = __builtin_amdgcn_mfma_f32_16x16x32_bf16(u1.v, Bf, acc[1][nt], 0, 0, 0);
      }
    }
    #pragma unroll
    for (int m = 0; m < 2; ++m)
      #pragma unroll
      for (int n = 0; n < 3; ++n)
        #pragma unroll
        for (int e = 0; e < 4; ++e)
          red[wv][m*16 + r0 + e][n*16 + cc] = acc[m][n][e];
    __syncthreads();
    float hnew[2];
    #pragma unroll
    for (int u2 = 0; u2 < 2; ++u2){
      int jj = jp*2 + u2;
      float r_ = 0.f, z_ = 0.f, n_ = 0.f;
      #pragma unroll
      for (int w = 0; w < 4; ++w){
        r_ += red[w][b][jj]; z_ += red[w][b][16+jj]; n_ += red[w][b][32+jj];
      }
      const float* gr = gi + ((size_t)(c*BB) + b)*G6 + wg*16 + jj;
      float rr = fsigm(gr[0]    + bhh[0][u2] + r_);
      float zz = fsigm(gr[1024] + bhh[1][u2] + z_);
      float nn = ftanh(gr[2048] + rr*(bhh[2][u2] + n_));
      hnew[u2] = ftanh((1.f - zz)*nn + zz*hold[u2]);
      hold[u2] = hnew[u2];
    }
    {
      int kt = j0 >> 5, ln = (b & 15) + 16*((j0 >> 3) & 3), rg = j0 & 7, mt = b >> 4;
      unsigned pk = (unsigned)__builtin_bit_cast(unsigned short, (bf16_t)hnew[0])
                  | ((unsigned)__builtin_bit_cast(unsigned short, (bf16_t)hnew[1]) << 16);
      unsigned* dst = (unsigned*)(hdp + (size_t)((c+1)&1)*2*32*64*8 +
                                  (((size_t)(mt*32 + kt)*64 + ln)*8 + rg));
      ASTORE(dst, pk);
    }
    __syncthreads();
    if (tid == 0)
      ASTORE(dfh + wg*16, (unsigned)(c+1));
    if (wg < 16){
      {
        const unsigned int* fp = dfh + lane*16;
        unsigned tgt = (unsigned)(c+1);
        for(;;){
          unsigned v = ALOAD(fp);
          if (__ballot(v < tgt) == 0ull) break;
        }
      }
      f32x4 pacc[2] = {zero, zero};
      const bf16_t* hb2 = hdp + (size_t)((c+1)&1)*2*32*64*8;
      #pragma unroll
      for (int i = 0; i < 8; ++i){
        int kt = wv*8 + i;
        HU u0, u1;
        const unsigned long long* p0 = (const unsigned long long*)(hb2 + (((size_t)0*32 + kt)*64 + lane)*8);
        const unsigned long long* p1 = (const unsigned long long*)(hb2 + (((size_t)1*32 + kt)*64 + lane)*8);
        u0.u[0] = ALOAD(p0);     u0.u[1] = ALOAD(p0 + 1);
        u1.u[0] = ALOAD(p1);     u1.u[1] = ALOAD(p1 + 1);
        bf16x8 Bf = *reinterpret_cast<const bf16x8*>(Ppw + (((size_t)wg*32 + kt)*64 + lane)*8);
        pacc[0] = __builtin_amdgcn_mfma_f32_16x16x32_bf16(u0.v, Bf, pacc[0], 0, 0, 0);
        pacc[1] = __builtin_amdgcn_mfma_f32_16x16x32_bf16(u1.v, Bf, pacc[1], 0, 0, 0);
      }
      #pragma unroll
      for (int m = 0; m < 2; ++m)
        #pragma unroll
        for (int e = 0; e < 4; ++e)
          red[wv][m*16 + r0 + e][cc] = pacc[m][e];
      __syncthreads();
      {
        int colp = tid >> 5;
        float v0 = 0.f, v1 = 0.f;
        #pragma unroll
        for (int w = 0; w < 4; ++w){
          v0 += red[w][b][colp*2];
          v1 += red[w][b][colp*2+1];
        }
        int c0 = wg*16 + colp*2, c1 = c0 + 1;
        plred[colp][b][0] = v0*cls_w[c0]      + v1*cls_w[c1];
        plred[colp][b][1] = v0*cls_w[PP + c0] + v1*cls_w[PP + c1];
      }
      __syncthreads();
      if (tid < 32){
        float s0 = 0.f, s1 = 0.f;
        #pragma unroll
        for (int g = 0; g < 8; ++g){ s0 += plred[g][tid][0]; s1 += plred[g][tid][1]; }
        unsigned* dp = (unsigned*)(pl + (((size_t)c*16 + wg)*32 + tid)*2);
        ASTORE(dp,     __builtin_bit_cast(unsigned, s0));
        ASTORE(dp + 1, __builtin_bit_cast(unsigned, s1));
      }
      __syncthreads();
      if (tid == 0)
        ASTORE(dfpl + wg*16, (unsigned)(c+1));
    }
  }
  if (wg == 0){
    if (lane < 16){
      const unsigned int* fp = dfpl + lane*16;
      for(;;){
        unsigned v = ALOAD(fp);
        if (__ballot(v < 6u) == 0ull) break;
      }
    }
    __syncthreads();
    float* cr = (float*)red;
    cr[tid*2]   = proj_b[tid]*cls_w[tid];
    cr[tid*2+1] = proj_b[tid]*cls_w[PP + tid];
    __syncthreads();
    if (tid < 2){
      float s = 0.f;
      for (int i = 0; i < 256; ++i) s += cr[i*2 + tid];
      cv[tid] = s;
    }
    __syncthreads();
    if (tid < 32){
      for (int c = 0; c < 6; ++c){
        float a0 = cv[0] + cls_b[0], a1 = cv[1] + cls_b[1];
        for (int w = 0; w < 16; ++w){
          const unsigned* dp = (const unsigned*)(pl + (((size_t)c*16 + w)*32 + tid)*2);
          a0 += __builtin_bit_cast(float, ALOAD(dp));
          a1 += __builtin_bit_cast(float, ALOAD(dp + 1));
        }
        float mx = fmaxf(a0, a1);
        float ls = mx + logf(expf(a0 - mx) + expf(a1 - mx));
        out[((size_t)c*BB + tid)*2 + 0] = a0 - ls;
        out[((size_t)c*BB + tid)*2 + 1] = a1 - ls;
      }
    }
  }
}

// ================================= host ===================================================
extern "C" void kernel_launch(void* const* d_in, const int* in_sizes, int n_in,
                              void* d_out, int out_size, void* d_ws, size_t ws_size,
                              hipStream_t stream){
  const int*   seq          = (const int*)  d_in[0];
  const int*   seq_char     = (const int*)  d_in[1];
  const int*   classes      = (const int*)  d_in[2];
  const float* embed_w      = (const float*)d_in[3];
  const float* char_embed_w = (const float*)d_in[4];
  const float* class_embed_w= (const float*)d_in[5];
  const float* char_conv_w  = (const float*)d_in[6];
  const float* char_conv_b  = (const float*)d_in[7];
  const float* word_conv_w  = (const float*)d_in[8];
  const float* word_conv_b  = (const float*)d_in[9];
  const float* f_Wih = (const float*)d_in[10];
  const float* f_Whh = (const float*)d_in[11];
  const float* f_b   = (const float*)d_in[12];
  const float* b_Wih = (const float*)d_in[13];
  const float* b_Whh = (const float*)d_in[14];
  const float* b_b   = (const float*)d_in[15];
  const float* attend = (const float*)d_in[16];
  const float* d_Wih  = (const float*)d_in[17];
  const float* d_Whh  = (const float*)d_in[18];
  const float* d_bih  = (const float*)d_in[19];
  const float* d_bhh  = (const float*)d_in[20];
  const float* proj_w = (const float*)d_in[21];
  const float* proj_b = (const float*)d_in[22];
  const float* cls_w  = (const float*)d_in[23];
  const float* cls_b  = (const float*)d_in[24];
  float* out = (float*)d_out;

  char* wsb = (char*)d_ws;
  size_t off = 0;
  auto alloc = [&](size_t bytes) -> char* {
    char* p = wsb + off;
    off += (bytes + 255) & ~(size_t)255;
    return p;
  };
  // --- allocation layout BYTE-IDENTICAL to the proven R9 run ---
  unsigned int* flags = (unsigned int*)alloc(12288);   // lf@0 | dfh@1024 | dfpl@2048 (dwords)
  unsigned int* lf   = flags;
  unsigned int* dfh  = flags + 1024;
  unsigned int* dfpl = flags + 2048;
  unsigned int* xcc_tab = (unsigned int*)alloc(1024);  // 256 dwords
  unsigned int* modep   = (unsigned int*)alloc(256);   // 64 dwords
  bf16_t* hp  = (bf16_t*)alloc((size_t)2*2*2*16*64*8 * 2);         // 128 KB (zeroed)
  const int ZERO_DWORDS = 3072 + 256 + 64 + 32768;                 // 36160
  bf16_t* hdp = (bf16_t*)alloc((size_t)2*2*32*64*8 * 2);           // 128 KB
  bf16_t* Wp  = (bf16_t*)alloc((size_t)2*32*NKT*4*64*8 * 2);
  bf16_t* Whp = (bf16_t*)alloc((size_t)64*3*32*64*8 * 2);
  bf16_t* Ppw = (bf16_t*)alloc((size_t)16*32*64*8 * 2);
  bf16_t* xp  = (bf16_t*)alloc((size_t)128*2*NKTX*64*8 * 2);
  float* pl       = (float*)alloc((size_t)6*16*32*2*4);
  float* x        = (float*)alloc((size_t)BB*SS*EC*4);
  float* mask     = (float*)alloc((size_t)BB*SS*4);
  float* cbar     = (float*)alloc((size_t)4096*512*4);
  float* xbar     = (float*)alloc((size_t)BB*EC*64*4);
  float* conv_seq = (float*)alloc((size_t)BB*256*4);
  float* seq_repr = (float*)alloc((size_t)BB*SS*H2*4);
  float* ta       = (float*)alloc((size_t)6*H2*4);
  float* ctx      = (float*)alloc((size_t)6*BB*H2*4);
  float* inp      = (float*)alloc((size_t)192*1280*4);   // kept (unused) for layout parity
  float* gi       = (float*)alloc((size_t)192*G6*4);
  float* part_char= (float*)alloc((size_t)2*4096*64*4);  // kept (unused) for layout parity
  float* part_word= (float*)alloc((size_t)32*BB*256*4);
  float* part_gi  = (float*)alloc((size_t)4*192*G6*4);
  (void)ws_size; (void)in_sizes; (void)n_in; (void)out_size;
  (void)inp; (void)part_char;

  // merged zero + weight packs: 1792 + 6144 + 512 + 565 = 9013 blocks
  k_prep<<<9013, 64, 0, stream>>>(f_Wih, f_Whh, b_Wih, b_Whh, Wp,
                                  d_Whh, Whp, proj_w, Ppw,
                                  (unsigned int*)d_ws, ZERO_DWORDS);
  k_embed_cbar<<<BB*SS, 256, 0, stream>>>(seq, embed_w, seq_char, char_embed_w, x, mask, cbar);
  k_cgemm<<<128, 256, 0, stream>>>(cbar, char_conv_w, char_conv_b, x);
  k_xbar<<<160, 64, 0, stream>>>(x, xbar);
  k_gemm<32,64,2,4><<<dim3(1,4,32), 256, 0, stream>>>(xbar, word_conv_w, part_word, 32, 256, 20480, 640);
  k_fin<<<dim3(4,32), 64, 0, stream>>>(part_word, word_conv_b, conv_seq, 32, 256, 32, 256, 1);
  k_packx<<<128*2*NKTX, 64, 0, stream>>>(x, xp);
  k_lstm<<<256, 256, 0, stream>>>(Wp, xp, hp, f_b, b_b, seq_repr, lf, xcc_tab, modep,
                                  hdp, classes, class_embed_w, attend, ta);
  k_ctx<<<dim3(6,32), 256, 0, stream>>>(ta, seq_repr, mask, ctx);
  k_gemmgi<<<dim3(3,48,4), 256, 0, stream>>>(conv_seq, ctx, d_Wih, part_gi);
  k_fin<<<dim3(48,192), 64, 0, stream>>>(part_gi, d_bih, gi, 192, G6, 4, G6, 0);
  k_dec<<<64, 256, 0, stream>>>(Whp, Ppw, gi, d_bhh, seq_repr, proj_b, cls_w, cls_b,
                                hdp, pl, dfh, dfpl, out);
}